// Round 1
// baseline (1655.841 us; speedup 1.0000x reference)
//
#include <hip/hip_runtime.h>

// TransitionGNN forward, fp32 baseline.
// B=1024 graphs, K=10 objects, D=32, H=512, A=4. Nodes N=10240, edges/graph=90.
//
// Pipeline:
//  K1a: P = X @ ew1[0:32,:]          (gemm512)
//  K1b: Q = X @ ew1[32:64,:]         (gemm512)
//  K2 : per-graph edge kernel: h1=relu(P[i]+Q[j]+eb1); h2=relu(LN(h1@ew2+eb2)*eg+ebt);
//       S[node] = sum over 9 out-edges of h2                 (fused, LDS-resident)
//  K3 : agg = S @ ew3 + 9*eb3  -> NIN[:,36:548]              (gemm512, bias_scale=9)
//  K4 : NIN[:,0:36] = [X | onehot(action)]                   (concat36)
//  K5 : Hh = relu(NIN @ nw1 + nb1)                           (gemm512, K=548)
//  K6 : H2 = relu(LN(Hh @ nw2 + nb2)*ng+nbt)                 (gemm512 + LN)
//  K7 : out = H2 @ nw3 + nb3                                 (out_kernel, N=32)

#define HID 512
#define DIN 32
#define KOBJ 10
#define NGRAPH 1024
#define NNODES (NGRAPH*KOBJ)
#define LN_EPS 1e-5f

// ---------------------------------------------------------------------------
// Generic row-block GEMM, N fixed = 512. Block: 512 threads, tile 48 rows.
// thread t -> wave tr=t>>6 owns rows tr*6..tr*6+5 (whole rows in one wave for LN),
// lane tc=t&63 owns cols tc*8..tc*8+7. acc[6][8] per thread.
template<bool DO_LN, bool DO_RELU>
__global__ __launch_bounds__(512) void gemm512(
    const float* __restrict__ A, int lda, int M, int Kdim,
    const float* __restrict__ W,            // [Kdim, 512] row-major
    const float* __restrict__ bias, float bias_scale,
    const float* __restrict__ gamma, const float* __restrict__ beta,
    float* __restrict__ out, int ldo)
{
    __shared__ float At[48][16];    // 3 KB
    __shared__ float Bt[16][512];   // 32 KB
    const int t  = threadIdx.x;
    const int tr = t >> 6, tc = t & 63;
    const int rowbase = blockIdx.x * 48;

    float acc[6][8];
#pragma unroll
    for (int i = 0; i < 6; ++i)
#pragma unroll
        for (int j = 0; j < 8; ++j) acc[i][j] = 0.f;

    const int nk = (Kdim + 15) >> 4;
    for (int kt = 0; kt < nk; ++kt) {
        const int k0 = kt << 4;
        // stage A tile: 48x16
        for (int l = t; l < 768; l += 512) {
            int r = l >> 4, kk = l & 15;
            int gr = rowbase + r, gk = k0 + kk;
            At[r][kk] = (gr < M && gk < Kdim) ? A[(size_t)gr * lda + gk] : 0.f;
        }
        // stage B tile: 16x512 (coalesced)
        for (int l = t; l < 8192; l += 512) {
            int r = l >> 9, c = l & 511;
            int gk = k0 + r;
            Bt[r][c] = (gk < Kdim) ? W[(size_t)gk * 512 + c] : 0.f;
        }
        __syncthreads();
#pragma unroll
        for (int kk = 0; kk < 16; ++kk) {
            float4 b0 = *(const float4*)&Bt[kk][tc * 8];
            float4 b1 = *(const float4*)&Bt[kk][tc * 8 + 4];
            float bv[8] = {b0.x, b0.y, b0.z, b0.w, b1.x, b1.y, b1.z, b1.w};
#pragma unroll
            for (int i = 0; i < 6; ++i) {
                float a = At[tr * 6 + i][kk];
#pragma unroll
                for (int j = 0; j < 8; ++j) acc[i][j] = fmaf(a, bv[j], acc[i][j]);
            }
        }
        __syncthreads();
    }

    // epilogue
    const int c0 = tc * 8;
    float bv[8];
#pragma unroll
    for (int j = 0; j < 8; ++j) bv[j] = bias ? bias_scale * bias[c0 + j] : 0.f;
    float gamm[8], bet[8];
    if constexpr (DO_LN) {
#pragma unroll
        for (int j = 0; j < 8; ++j) { gamm[j] = gamma[c0 + j]; bet[j] = beta[c0 + j]; }
    }
#pragma unroll
    for (int i = 0; i < 6; ++i) {
        int gr = rowbase + tr * 6 + i;
        float v[8];
#pragma unroll
        for (int j = 0; j < 8; ++j) v[j] = acc[i][j] + bv[j];
        if constexpr (DO_LN) {
            float s = 0.f, ss = 0.f;
#pragma unroll
            for (int j = 0; j < 8; ++j) { s += v[j]; ss += v[j] * v[j]; }
#pragma unroll
            for (int m = 1; m < 64; m <<= 1) {
                s  += __shfl_xor(s, m, 64);
                ss += __shfl_xor(ss, m, 64);
            }
            float mean = s * (1.f / 512.f);
            float var  = ss * (1.f / 512.f) - mean * mean;
            float inv  = rsqrtf(var + LN_EPS);
#pragma unroll
            for (int j = 0; j < 8; ++j) v[j] = (v[j] - mean) * inv * gamm[j] + bet[j];
        }
        if constexpr (DO_RELU) {
#pragma unroll
            for (int j = 0; j < 8; ++j) v[j] = fmaxf(v[j], 0.f);
        }
        if (gr < M) {
            float4* o = (float4*)&out[(size_t)gr * ldo + c0];
            o[0] = make_float4(v[0], v[1], v[2], v[3]);
            o[1] = make_float4(v[4], v[5], v[6], v[7]);
        }
    }
}

// ---------------------------------------------------------------------------
// Edge kernel: one block per graph. 90 edges (padded to 96). For each edge
// e=(i,j): h1 = relu(P[i]+Q[j]+eb1) built on the fly per k-tile (P,Q rows are
// L1/L2-hot), GEMM vs ew2, add eb2, per-row LayerNorm (wave shuffle), scale
// eg/ebt, relu, then per-source-node sum into LDS, write S.
__global__ __launch_bounds__(512) void edge_kernel(
    const float* __restrict__ P, const float* __restrict__ Q,
    const float* __restrict__ eb1, const float* __restrict__ ew2,
    const float* __restrict__ eb2, const float* __restrict__ eg,
    const float* __restrict__ ebt, float* __restrict__ S)
{
    __shared__ float At[96][16];        // 6 KB  (h1 tile)
    __shared__ float Bt[16][512];       // 32 KB (ew2 tile)
    __shared__ float Sl[KOBJ][512];     // 20 KB (per-node sums)
    const int t  = threadIdx.x;
    const int tr = t >> 6, tc = t & 63;
    const size_t nbase = (size_t)blockIdx.x * KOBJ * HID;

    for (int l = t; l < KOBJ * HID; l += 512) ((float*)Sl)[l] = 0.f;

    float acc[12][8];
#pragma unroll
    for (int i = 0; i < 12; ++i)
#pragma unroll
        for (int j = 0; j < 8; ++j) acc[i][j] = 0.f;

    for (int kt = 0; kt < 32; ++kt) {
        const int k0 = kt << 4;
        for (int l = t; l < 8192; l += 512) {
            int r = l >> 9, c = l & 511;
            Bt[r][c] = ew2[(size_t)(k0 + r) * 512 + c];
        }
        for (int l = t; l < 1536; l += 512) {
            int r = l >> 4, kk = l & 15;
            float v = 0.f;
            if (r < 90) {
                int i = r / 9, jj = r - i * 9;
                int j = jj + (jj >= i);
                float p = P[nbase + i * HID + k0 + kk];
                float q = Q[nbase + j * HID + k0 + kk];
                v = fmaxf(p + q + eb1[k0 + kk], 0.f);
            }
            At[r][kk] = v;
        }
        __syncthreads();
#pragma unroll
        for (int kk = 0; kk < 16; ++kk) {
            float4 b0 = *(const float4*)&Bt[kk][tc * 8];
            float4 b1 = *(const float4*)&Bt[kk][tc * 8 + 4];
            float bvv[8] = {b0.x, b0.y, b0.z, b0.w, b1.x, b1.y, b1.z, b1.w};
#pragma unroll
            for (int i = 0; i < 12; ++i) {
                float a = At[tr * 12 + i][kk];
#pragma unroll
                for (int j = 0; j < 8; ++j) acc[i][j] = fmaf(a, bvv[j], acc[i][j]);
            }
        }
        __syncthreads();
    }

    const int c0 = tc * 8;
    float b2[8], gb[8], bb[8];
#pragma unroll
    for (int j = 0; j < 8; ++j) {
        b2[j] = eb2[c0 + j]; gb[j] = eg[c0 + j]; bb[j] = ebt[c0 + j];
    }
#pragma unroll
    for (int i = 0; i < 12; ++i) {
        int r = tr * 12 + i;
        float v[8];
#pragma unroll
        for (int j = 0; j < 8; ++j) v[j] = acc[i][j] + b2[j];
        float s = 0.f, ss = 0.f;
#pragma unroll
        for (int j = 0; j < 8; ++j) { s += v[j]; ss += v[j] * v[j]; }
#pragma unroll
        for (int m = 1; m < 64; m <<= 1) {
            s  += __shfl_xor(s, m, 64);
            ss += __shfl_xor(ss, m, 64);
        }
        float mean = s * (1.f / 512.f);
        float var  = ss * (1.f / 512.f) - mean * mean;
        float inv  = rsqrtf(var + LN_EPS);
        if (r < 90) {
            int node = r / 9;
#pragma unroll
            for (int j = 0; j < 8; ++j) {
                float h = fmaxf((v[j] - mean) * inv * gb[j] + bb[j], 0.f);
                atomicAdd(&Sl[node][c0 + j], h);
            }
        }
    }
    __syncthreads();
    for (int l = t; l < KOBJ * HID; l += 512) S[nbase + l] = ((float*)Sl)[l];
}

// ---------------------------------------------------------------------------
// Fill NIN[:,0:36] = [X(32) | onehot(action)(4)]
__global__ void concat36(const float* __restrict__ X, const int* __restrict__ act,
                         float* __restrict__ NIN)
{
    int idx = blockIdx.x * 256 + threadIdx.x;
    if (idx >= NNODES * 36) return;
    int r = idx / 36, c = idx - 36 * r;
    float v;
    if (c < DIN) v = X[(size_t)r * DIN + c];
    else         v = (act[r / KOBJ] == (c - DIN)) ? 1.f : 0.f;
    NIN[(size_t)r * 548 + c] = v;
}

// ---------------------------------------------------------------------------
// out[10240,32] = H2 @ nw3 + nb3.  Block 256 = 8 rows x 32 cols.
__global__ __launch_bounds__(256) void out_kernel(
    const float* __restrict__ H2, const float* __restrict__ W3,
    const float* __restrict__ b3, float* __restrict__ out)
{
    int t = threadIdx.x;
    int r = blockIdx.x * 8 + (t >> 5);
    int c = t & 31;
    const float* hrow = H2 + (size_t)r * HID;
    float acc = 0.f;
#pragma unroll 8
    for (int k = 0; k < HID; ++k) acc = fmaf(hrow[k], W3[k * DIN + c], acc);
    out[(size_t)r * DIN + c] = acc + b3[c];
}

// ---------------------------------------------------------------------------
extern "C" void kernel_launch(void* const* d_in, const int* in_sizes, int n_in,
                              void* d_out, int out_size, void* d_ws, size_t ws_size,
                              hipStream_t stream)
{
    const float* states = (const float*)d_in[0];
    const int*   action = (const int*)d_in[1];
    const float* ew1 = (const float*)d_in[2];
    const float* eb1 = (const float*)d_in[3];
    const float* ew2 = (const float*)d_in[4];
    const float* eb2 = (const float*)d_in[5];
    const float* eg  = (const float*)d_in[6];
    const float* ebt = (const float*)d_in[7];
    const float* ew3 = (const float*)d_in[8];
    const float* eb3 = (const float*)d_in[9];
    const float* nw1 = (const float*)d_in[10];
    const float* nb1 = (const float*)d_in[11];
    const float* nw2 = (const float*)d_in[12];
    const float* nb2 = (const float*)d_in[13];
    const float* ng  = (const float*)d_in[14];
    const float* nbt = (const float*)d_in[15];
    const float* nw3 = (const float*)d_in[16];
    const float* nb3 = (const float*)d_in[17];

    float* ws  = (float*)d_ws;
    float* P   = ws;                         // 10240*512
    float* Q   = ws + 5242880;               // 10240*512
    float* S   = ws + 10485760;              // 10240*512
    float* NIN = ws + 15728640;              // 10240*548
    float* Hh  = P;                          // reuse after edge kernel
    float* H2  = Q;                          // reuse
    float* out = (float*)d_out;

    const dim3 blk(512);
    const int mb = (NNODES + 47) / 48;       // 214

    // P = X @ ew1[0:32,:],  Q = X @ ew1[32:64,:]
    hipLaunchKernelGGL((gemm512<false, false>), dim3(mb), blk, 0, stream,
                       states, DIN, NNODES, DIN, ew1, nullptr, 0.f, nullptr, nullptr, P, HID);
    hipLaunchKernelGGL((gemm512<false, false>), dim3(mb), blk, 0, stream,
                       states, DIN, NNODES, DIN, ew1 + DIN * HID, nullptr, 0.f, nullptr, nullptr, Q, HID);
    // fused edge MLP layer 2 + LN + relu + per-node aggregation
    hipLaunchKernelGGL(edge_kernel, dim3(NGRAPH), blk, 0, stream,
                       P, Q, eb1, ew2, eb2, eg, ebt, S);
    // agg = S @ ew3 + 9*eb3  -> NIN[:,36:]
    hipLaunchKernelGGL((gemm512<false, false>), dim3(mb), blk, 0, stream,
                       S, HID, NNODES, HID, ew3, eb3, 9.f, nullptr, nullptr, NIN + 36, 548);
    // NIN[:,0:36] = [X | onehot]
    hipLaunchKernelGGL(concat36, dim3((NNODES * 36 + 255) / 256), dim3(256), 0, stream,
                       states, action, NIN);
    // Hh = relu(NIN @ nw1 + nb1)
    hipLaunchKernelGGL((gemm512<false, true>), dim3(mb), blk, 0, stream,
                       NIN, 548, NNODES, 548, nw1, nb1, 1.f, nullptr, nullptr, Hh, HID);
    // H2 = relu(LN(Hh @ nw2 + nb2)*ng + nbt)
    hipLaunchKernelGGL((gemm512<true, true>), dim3(mb), blk, 0, stream,
                       Hh, HID, NNODES, HID, nw2, nb2, 1.f, ng, nbt, H2, HID);
    // out = H2 @ nw3 + nb3
    hipLaunchKernelGGL(out_kernel, dim3(NNODES / 8), dim3(256), 0, stream,
                       H2, nw3, nb3, out);
}

// Round 3
// 523.846 us; speedup vs baseline: 3.1609x; 3.1609x over previous
//
#include <hip/hip_runtime.h>

// TransitionGNN forward, bf16-MFMA version.
// B=1024 graphs, K=10 objects, D=32, H=512. Nodes N=10240, 90 edges/graph.
//
//  pack   : ew2,ew3,nw2,nw1 -> bf16 fragment-packed Wp[k/8][col][8]
//  K1a/b  : P = X @ ew1[0:32,:], Q = X @ ew1[32:64,:]      (fp32 VALU, small)
//  K2     : edge_mfma: per half-graph (45 edges): h1=relu(P[i]+Q[j]+eb1) in-reg,
//           C=h1@ew2 (MFMA), +eb2, LN, *eg+ebt, relu, aggregate -> S bf16
//  K3     : NIN[:,64:576] = S @ ew3 + 9*eb3                (MFMA, bf16 out)
//  K4     : NIN[:,0:64]   = [X | onehot | zeros]           (bf16)
//  K5     : Hh = relu(NIN @ nw1 + nb1)                     (MFMA, K=576)
//  K6     : H2 = relu(LN(Hh @ nw2 + nb2)*ng+nbt)           (MFMA, f32 out)
//  K7     : out = H2 @ nw3 + nb3                           (fp32 VALU, small)

#define HID 512
#define DIN 32
#define KOBJ 10
#define NGRAPH 1024
#define NNODES (NGRAPH*KOBJ)
#define LN_EPS 1e-5f

typedef __bf16 bf16x8 __attribute__((ext_vector_type(8)));
typedef unsigned short u16x8 __attribute__((ext_vector_type(8)));
typedef float f32x4 __attribute__((ext_vector_type(4)));

__device__ __forceinline__ unsigned short f2bf(float f) {
    unsigned u = __builtin_bit_cast(unsigned, f);
    u += 0x7fffu + ((u >> 16) & 1u);          // RNE
    return (unsigned short)(u >> 16);
}

// ---------------------------------------------------------------------------
// Weight packing: dst[idx] with idx=(kb*512+c)*8+j  <=  bf16(src[(kb*8+j)*512+c])
__global__ void pack_w(const float* __restrict__ src, unsigned short* __restrict__ dst, int n)
{
    int idx = blockIdx.x * 256 + threadIdx.x;
    if (idx >= n) return;
    int j = idx & 7, c = (idx >> 3) & 511, kb = idx >> 12;
    dst[idx] = f2bf(src[(size_t)(kb * 8 + j) * 512 + c]);
}

// nw1 packed with row remap: k<36 -> k ; 36..63 -> zero ; k>=64 -> k-28
__global__ void pack_nw1(const float* __restrict__ src, unsigned short* __restrict__ dst)
{
    int idx = blockIdx.x * 256 + threadIdx.x;
    if (idx >= 576 * 512) return;
    int j = idx & 7, c = (idx >> 3) & 511, kb = idx >> 12;
    int k = kb * 8 + j;
    int sk = (k < 36) ? k : (k < 64 ? -1 : k - 28);
    dst[idx] = f2bf(sk < 0 ? 0.f : src[(size_t)sk * 512 + c]);
}

// ---------------------------------------------------------------------------
// fp32 row-block GEMM for tiny-K P/Q (K=32). No LN.
__global__ __launch_bounds__(512) void gemm512(
    const float* __restrict__ A, int lda, int M, int Kdim,
    const float* __restrict__ W, float* __restrict__ out, int ldo)
{
    __shared__ float At[48][16];
    __shared__ float Bt[16][512];
    const int t = threadIdx.x;
    const int tr = t >> 6, tc = t & 63;
    const int rowbase = blockIdx.x * 48;

    float acc[6][8];
#pragma unroll
    for (int i = 0; i < 6; ++i)
#pragma unroll
        for (int j = 0; j < 8; ++j) acc[i][j] = 0.f;

    const int nk = (Kdim + 15) >> 4;
    for (int kt = 0; kt < nk; ++kt) {
        const int k0 = kt << 4;
        for (int l = t; l < 768; l += 512) {
            int r = l >> 4, kk = l & 15;
            int gr = rowbase + r, gk = k0 + kk;
            At[r][kk] = (gr < M && gk < Kdim) ? A[(size_t)gr * lda + gk] : 0.f;
        }
        for (int l = t; l < 8192; l += 512) {
            int r = l >> 9, c = l & 511;
            int gk = k0 + r;
            Bt[r][c] = (gk < Kdim) ? W[(size_t)gk * 512 + c] : 0.f;
        }
        __syncthreads();
#pragma unroll
        for (int kk = 0; kk < 16; ++kk) {
            float4 b0 = *(const float4*)&Bt[kk][tc * 8];
            float4 b1 = *(const float4*)&Bt[kk][tc * 8 + 4];
            float bv[8] = {b0.x, b0.y, b0.z, b0.w, b1.x, b1.y, b1.z, b1.w};
#pragma unroll
            for (int i = 0; i < 6; ++i) {
                float a = At[tr * 6 + i][kk];
#pragma unroll
                for (int j = 0; j < 8; ++j) acc[i][j] = fmaf(a, bv[j], acc[i][j]);
            }
        }
        __syncthreads();
    }
    const int c0 = tc * 8;
#pragma unroll
    for (int i = 0; i < 6; ++i) {
        int gr = rowbase + tr * 6 + i;
        if (gr < M) {
            float4* o = (float4*)&out[(size_t)gr * ldo + c0];
            o[0] = make_float4(acc[i][0], acc[i][1], acc[i][2], acc[i][3]);
            o[1] = make_float4(acc[i][4], acc[i][5], acc[i][6], acc[i][7]);
        }
    }
}

// ---------------------------------------------------------------------------
// Edge MFMA kernel. Grid 2048 = 2 blocks/graph (45 edges = 5 source nodes each).
// Block 256 thr = 4 waves; wave w owns cols w*128..w*128+127 (8 n-tiles),
// rows 0..47 (3 m-tiles, rows 45-47 dead).
__global__ __launch_bounds__(256) void edge_mfma(
    const float* __restrict__ P, const float* __restrict__ Q,
    const float* __restrict__ eb1, const unsigned short* __restrict__ ew2p,
    const float* __restrict__ eb2, const float* __restrict__ eg,
    const float* __restrict__ ebt, unsigned short* __restrict__ S)
{
    __shared__ float Sl[5][512];
    __shared__ float sums[48], ssums[48];
    const int t = threadIdx.x;
    const int w = t >> 6, l = t & 63;
    const int lr = l & 15, lg = l >> 4;
    const int g = blockIdx.x >> 1, half = blockIdx.x & 1;

    for (int i = t; i < 5 * 512; i += 256) ((float*)Sl)[i] = 0.f;
    if (t < 48) { sums[t] = 0.f; ssums[t] = 0.f; }
    __syncthreads();

    // per m-tile: this lane's A-row (edge) -> P row i, Q row j
    const float* prow[3];
    const float* qrow[3];
    bool valid[3];
#pragma unroll
    for (int m = 0; m < 3; ++m) {
        int r = m * 16 + lr;                 // edge row within half (0..47)
        valid[m] = (r < 45);
        int rr = valid[m] ? r : 0;
        int e = half * 45 + rr;              // edge within graph 0..89
        int i = e / 9, jj = e - i * 9;
        int j = jj + (jj >= i);
        prow[m] = P + ((size_t)g * KOBJ + i) * HID;
        qrow[m] = Q + ((size_t)g * KOBJ + j) * HID;
    }

    f32x4 acc[3][8] = {};
    const int ksub = lg * 8;

    for (int kc = 0; kc < 16; ++kc) {
        const int koff = kc * 32 + ksub;
        float4 e0 = *(const float4*)(eb1 + koff);
        float4 e1 = *(const float4*)(eb1 + koff + 4);
        bf16x8 afr[3];
#pragma unroll
        for (int m = 0; m < 3; ++m) {
            float4 p0 = *(const float4*)(prow[m] + koff);
            float4 p1 = *(const float4*)(prow[m] + koff + 4);
            float4 q0 = *(const float4*)(qrow[m] + koff);
            float4 q1 = *(const float4*)(qrow[m] + koff + 4);
            u16x8 u;
            u[0] = f2bf(fmaxf(p0.x + q0.x + e0.x, 0.f));
            u[1] = f2bf(fmaxf(p0.y + q0.y + e0.y, 0.f));
            u[2] = f2bf(fmaxf(p0.z + q0.z + e0.z, 0.f));
            u[3] = f2bf(fmaxf(p0.w + q0.w + e0.w, 0.f));
            u[4] = f2bf(fmaxf(p1.x + q1.x + e1.x, 0.f));
            u[5] = f2bf(fmaxf(p1.y + q1.y + e1.y, 0.f));
            u[6] = f2bf(fmaxf(p1.z + q1.z + e1.z, 0.f));
            u[7] = f2bf(fmaxf(p1.w + q1.w + e1.w, 0.f));
            if (!valid[m]) u = (u16x8)(unsigned short)0;
            afr[m] = __builtin_bit_cast(bf16x8, u);
        }
        const size_t kb = (size_t)(kc * 4 + lg) * 512;
#pragma unroll
        for (int nt = 0; nt < 8; ++nt) {
            int c = w * 128 + nt * 16 + lr;
            bf16x8 bfr = __builtin_bit_cast(bf16x8, *(const u16x8*)(ew2p + (kb + c) * 8));
            acc[0][nt] = __builtin_amdgcn_mfma_f32_16x16x32_bf16(afr[0], bfr, acc[0][nt], 0, 0, 0);
            acc[1][nt] = __builtin_amdgcn_mfma_f32_16x16x32_bf16(afr[1], bfr, acc[1][nt], 0, 0, 0);
            acc[2][nt] = __builtin_amdgcn_mfma_f32_16x16x32_bf16(afr[2], bfr, acc[2][nt], 0, 0, 0);
        }
    }

    // epilogue: +eb2, LN row stats (rows r = m*16 + lg*4 + reg)
    float b2[8], gb[8], bb[8];
#pragma unroll
    for (int nt = 0; nt < 8; ++nt) {
        int c = w * 128 + nt * 16 + lr;
        b2[nt] = eb2[c]; gb[nt] = eg[c]; bb[nt] = ebt[c];
    }
#pragma unroll
    for (int m = 0; m < 3; ++m)
#pragma unroll
        for (int reg = 0; reg < 4; ++reg) {
            float s = 0.f, ss = 0.f;
#pragma unroll
            for (int nt = 0; nt < 8; ++nt) {
                float v = acc[m][nt][reg] + b2[nt];
                acc[m][nt][reg] = v;
                s += v; ss += v * v;
            }
#pragma unroll
            for (int msk = 1; msk < 16; msk <<= 1) {
                s  += __shfl_xor(s,  msk, 64);
                ss += __shfl_xor(ss, msk, 64);
            }
            if (lr == 0) {
                atomicAdd(&sums [m * 16 + lg * 4 + reg], s);
                atomicAdd(&ssums[m * 16 + lg * 4 + reg], ss);
            }
        }
    __syncthreads();

#pragma unroll
    for (int m = 0; m < 3; ++m)
#pragma unroll
        for (int reg = 0; reg < 4; ++reg) {
            int r = m * 16 + lg * 4 + reg;
            float mean = sums[r] * (1.f / 512.f);
            float var  = ssums[r] * (1.f / 512.f) - mean * mean;
            float inv  = rsqrtf(var + LN_EPS);
            if (r < 45) {
                int node = r / 9;            // local source node 0..4
#pragma unroll
                for (int nt = 0; nt < 8; ++nt) {
                    float h = fmaxf((acc[m][nt][reg] - mean) * inv * gb[nt] + bb[nt], 0.f);
                    atomicAdd(&Sl[node][w * 128 + nt * 16 + lr], h);
                }
            }
        }
    __syncthreads();

    const size_t sbase = ((size_t)g * KOBJ + half * 5) * HID;
    for (int i = t; i < 5 * 512; i += 256) S[sbase + i] = f2bf(((float*)Sl)[i]);
}

// ---------------------------------------------------------------------------
// Node MFMA GEMM: C[M x 512] = A(bf16)[M x lda] @ Wp + epilogue.
// Block 512 thr = 8 waves, 48 rows/block. Wave w: cols w*64 (4 n-tiles).
// MODE 0: +bias*scale, bf16 out. MODE 1: +bias, relu, bf16 out.
// MODE 2: +bias, LN(gamma,beta), relu, f32 out.
template<int MODE>
__global__ __launch_bounds__(512) void node_mfma(
    const unsigned short* __restrict__ A, int lda, int nk,
    const unsigned short* __restrict__ Wp,
    const float* __restrict__ bias, float bscale,
    const float* __restrict__ gamma, const float* __restrict__ beta,
    unsigned short* __restrict__ outb, float* __restrict__ outf, int ldo, int ocol)
{
    __shared__ float sums[48], ssums[48];
    const int t = threadIdx.x, w = t >> 6, l = t & 63;
    const int lr = l & 15, lg = l >> 4;
    const int rowbase = blockIdx.x * 48;
    if constexpr (MODE == 2) {
        if (t < 48) { sums[t] = 0.f; ssums[t] = 0.f; }
        __syncthreads();
    }

    const unsigned short* arow[3];
#pragma unroll
    for (int m = 0; m < 3; ++m) {
        int r = rowbase + m * 16 + lr;
        if (r > NNODES - 1) r = NNODES - 1;
        arow[m] = A + (size_t)r * lda + lg * 8;
    }

    f32x4 acc[3][4] = {};
    for (int kc = 0; kc < nk; ++kc) {
        bf16x8 afr[3];
#pragma unroll
        for (int m = 0; m < 3; ++m)
            afr[m] = __builtin_bit_cast(bf16x8, *(const u16x8*)(arow[m] + kc * 32));
        const size_t kb = (size_t)(kc * 4 + lg) * 512;
#pragma unroll
        for (int nt = 0; nt < 4; ++nt) {
            int c = w * 64 + nt * 16 + lr;
            bf16x8 bfr = __builtin_bit_cast(bf16x8, *(const u16x8*)(Wp + (kb + c) * 8));
            acc[0][nt] = __builtin_amdgcn_mfma_f32_16x16x32_bf16(afr[0], bfr, acc[0][nt], 0, 0, 0);
            acc[1][nt] = __builtin_amdgcn_mfma_f32_16x16x32_bf16(afr[1], bfr, acc[1][nt], 0, 0, 0);
            acc[2][nt] = __builtin_amdgcn_mfma_f32_16x16x32_bf16(afr[2], bfr, acc[2][nt], 0, 0, 0);
        }
    }

    float bv[4];
#pragma unroll
    for (int nt = 0; nt < 4; ++nt) bv[nt] = bias[w * 64 + nt * 16 + lr] * bscale;

    if constexpr (MODE != 2) {
#pragma unroll
        for (int m = 0; m < 3; ++m)
#pragma unroll
            for (int reg = 0; reg < 4; ++reg) {
                int r = rowbase + m * 16 + lg * 4 + reg;
                if (r < NNODES) {
#pragma unroll
                    for (int nt = 0; nt < 4; ++nt) {
                        float v = acc[m][nt][reg] + bv[nt];
                        if constexpr (MODE == 1) v = fmaxf(v, 0.f);
                        outb[(size_t)r * ldo + ocol + w * 64 + nt * 16 + lr] = f2bf(v);
                    }
                }
            }
    } else {
        float gv[4], be[4];
#pragma unroll
        for (int nt = 0; nt < 4; ++nt) {
            int c = w * 64 + nt * 16 + lr;
            gv[nt] = gamma[c]; be[nt] = beta[c];
        }
#pragma unroll
        for (int m = 0; m < 3; ++m)
#pragma unroll
            for (int reg = 0; reg < 4; ++reg) {
                float s = 0.f, ss = 0.f;
#pragma unroll
                for (int nt = 0; nt < 4; ++nt) {
                    float v = acc[m][nt][reg] + bv[nt];
                    acc[m][nt][reg] = v;
                    s += v; ss += v * v;
                }
#pragma unroll
                for (int msk = 1; msk < 16; msk <<= 1) {
                    s  += __shfl_xor(s,  msk, 64);
                    ss += __shfl_xor(ss, msk, 64);
                }
                if (lr == 0) {
                    atomicAdd(&sums [m * 16 + lg * 4 + reg], s);
                    atomicAdd(&ssums[m * 16 + lg * 4 + reg], ss);
                }
            }
        __syncthreads();
#pragma unroll
        for (int m = 0; m < 3; ++m)
#pragma unroll
            for (int reg = 0; reg < 4; ++reg) {
                int rl = m * 16 + lg * 4 + reg;
                int r = rowbase + rl;
                float mean = sums[rl] * (1.f / 512.f);
                float var  = ssums[rl] * (1.f / 512.f) - mean * mean;
                float inv  = rsqrtf(var + LN_EPS);
                if (r < NNODES) {
#pragma unroll
                    for (int nt = 0; nt < 4; ++nt) {
                        float v = fmaxf((acc[m][nt][reg] - mean) * inv * gv[nt] + be[nt], 0.f);
                        outf[(size_t)r * ldo + w * 64 + nt * 16 + lr] = v;
                    }
                }
            }
    }
}

// ---------------------------------------------------------------------------
// NIN[:,0:64] = [X(32) | onehot(4) | zeros(28)]  (bf16)
__global__ void concat64(const float* __restrict__ X, const int* __restrict__ act,
                         unsigned short* __restrict__ NIN)
{
    int idx = blockIdx.x * 256 + threadIdx.x;
    if (idx >= NNODES * 64) return;
    int r = idx >> 6, c = idx & 63;
    float v = 0.f;
    if (c < DIN) v = X[(size_t)r * DIN + c];
    else if (c < DIN + 4) v = (act[r / KOBJ] == (c - DIN)) ? 1.f : 0.f;
    NIN[(size_t)r * 576 + c] = f2bf(v);
}

// ---------------------------------------------------------------------------
// out[10240,32] = H2 @ nw3 + nb3 (fp32)
__global__ __launch_bounds__(256) void out_kernel(
    const float* __restrict__ H2, const float* __restrict__ W3,
    const float* __restrict__ b3, float* __restrict__ out)
{
    int t = threadIdx.x;
    int r = blockIdx.x * 8 + (t >> 5);
    int c = t & 31;
    const float* hrow = H2 + (size_t)r * HID;
    float acc = 0.f;
#pragma unroll 8
    for (int k = 0; k < HID; ++k) acc = fmaf(hrow[k], W3[k * DIN + c], acc);
    out[(size_t)r * DIN + c] = acc + b3[c];
}

// ---------------------------------------------------------------------------
extern "C" void kernel_launch(void* const* d_in, const int* in_sizes, int n_in,
                              void* d_out, int out_size, void* d_ws, size_t ws_size,
                              hipStream_t stream)
{
    const float* states = (const float*)d_in[0];
    const int*   action = (const int*)d_in[1];
    const float* ew1 = (const float*)d_in[2];
    const float* eb1 = (const float*)d_in[3];
    const float* ew2 = (const float*)d_in[4];
    const float* eb2 = (const float*)d_in[5];
    const float* eg  = (const float*)d_in[6];
    const float* ebt = (const float*)d_in[7];
    const float* ew3 = (const float*)d_in[8];
    const float* eb3 = (const float*)d_in[9];
    const float* nw1 = (const float*)d_in[10];
    const float* nb1 = (const float*)d_in[11];
    const float* nw2 = (const float*)d_in[12];
    const float* nb2 = (const float*)d_in[13];
    const float* ng  = (const float*)d_in[14];
    const float* nbt = (const float*)d_in[15];
    const float* nw3 = (const float*)d_in[16];
    const float* nb3 = (const float*)d_in[17];

    float* ws = (float*)d_ws;
    float*          P    = ws;                                   // 10240x512 f32
    float*          Q    = ws + 5242880;                         // 10240x512 f32
    unsigned short* S    = (unsigned short*)(ws + 10485760);     // 10240x512 bf16
    unsigned short* NIN  = (unsigned short*)(ws + 13107200);     // 10240x576 bf16
    unsigned short* ew2p = (unsigned short*)(ws + 16056320);     // 512x512 bf16 packed
    unsigned short* ew3p = (unsigned short*)(ws + 16187392);
    unsigned short* nw2p = (unsigned short*)(ws + 16318464);
    unsigned short* nw1p = (unsigned short*)(ws + 16449536);     // 576x512
    unsigned short* Hh   = (unsigned short*)P;                   // reuse
    float*          H2   = Q;                                    // reuse
    float*          out  = (float*)d_out;

    // pack weights (every call; deterministic)
    hipLaunchKernelGGL(pack_w, dim3(1024), dim3(256), 0, stream, ew2, ew2p, 512 * 512);
    hipLaunchKernelGGL(pack_w, dim3(1024), dim3(256), 0, stream, ew3, ew3p, 512 * 512);
    hipLaunchKernelGGL(pack_w, dim3(1024), dim3(256), 0, stream, nw2, nw2p, 512 * 512);
    hipLaunchKernelGGL(pack_nw1, dim3(1152), dim3(256), 0, stream, nw1, nw1p);

    const int mb = (NNODES + 47) / 48;   // 214
    // P = X @ ew1[0:32,:], Q = X @ ew1[32:64,:]
    hipLaunchKernelGGL(gemm512, dim3(mb), dim3(512), 0, stream,
                       states, DIN, NNODES, DIN, ew1, P, HID);
    hipLaunchKernelGGL(gemm512, dim3(mb), dim3(512), 0, stream,
                       states, DIN, NNODES, DIN, ew1 + DIN * HID, Q, HID);
    // edge MLP (MFMA) + LN + relu + aggregate -> S (bf16)
    hipLaunchKernelGGL(edge_mfma, dim3(2 * NGRAPH), dim3(256), 0, stream,
                       P, Q, eb1, ew2p, eb2, eg, ebt, S);
    // NIN[:,64:576] = S @ ew3 + 9*eb3
    hipLaunchKernelGGL((node_mfma<0>), dim3(mb), dim3(512), 0, stream,
                       S, 512, 16, ew3p, eb3, 9.f, nullptr, nullptr, NIN, nullptr, 576, 64);
    // NIN[:,0:64]
    hipLaunchKernelGGL(concat64, dim3((NNODES * 64 + 255) / 256), dim3(256), 0, stream,
                       states, action, NIN);
    // Hh = relu(NIN @ nw1 + nb1)
    hipLaunchKernelGGL((node_mfma<1>), dim3(mb), dim3(512), 0, stream,
                       NIN, 576, 18, nw1p, nb1, 1.f, nullptr, nullptr, Hh, nullptr, 512, 0);
    // H2 = relu(LN(Hh @ nw2 + nb2)*ng + nbt)  (f32 out)
    hipLaunchKernelGGL((node_mfma<2>), dim3(mb), dim3(512), 0, stream,
                       Hh, 512, 16, nw2p, nb2, 1.f, ng, nbt, nullptr, H2, 512, 0);
    // out = H2 @ nw3 + nb3
    hipLaunchKernelGGL(out_kernel, dim3(NNODES / 8), dim3(256), 0, stream,
                       H2, nw3, nb3, out);
}

// Round 4
// 437.112 us; speedup vs baseline: 3.7881x; 1.1984x over previous
//
#include <hip/hip_runtime.h>

// TransitionGNN forward, v4: LDS-staged MFMA pipeline.
// B=1024 graphs, K=10 objects, D=32, H=512. Nodes N=10240, 90 edges/graph.
//
//  pack   : ew1 -> ew1p [32,1024] frag-packed; ew2,ew3,nw2 -> [k/8][512][8]; nw1 remapped
//  pq     : PQ[10240][1024] bf16 = X @ [ew1_P | ew1_Q]          (MFMA)
//  edge   : per graph (96 rows x 512 x K=512, BK=32, B dbuf in LDS via
//           global_load_lds, A=relu(P[i]+Q[j]+eb1) built from prefetched regs,
//           stride-40 LDS layout): +eb2, LN, *eg+ebt, relu, aggregate -> S bf16
//  node0  : NIN[:,64:576] = S @ ew3 + 9*eb3                      (MFMA, LDS-staged)
//  concat : NIN[:,0:64]   = [X | onehot | zeros]                 (bf16)
//  node1  : Hh = relu(NIN @ nw1 + nb1)   K=576
//  node2  : H2 = relu(LN(Hh @ nw2 + nb2)*ng+nbt)  (bf16 out)
//  out    : out = H2 @ nw3 + nb3  (f32)

#define HID 512
#define DIN 32
#define KOBJ 10
#define NGRAPH 1024
#define NNODES (NGRAPH*KOBJ)
#define LN_EPS 1e-5f

typedef __bf16 bf16x8 __attribute__((ext_vector_type(8)));
typedef unsigned short u16x8 __attribute__((ext_vector_type(8)));
typedef float f32x4 __attribute__((ext_vector_type(4)));

__device__ __forceinline__ unsigned short f2bf(float f) {
    unsigned u = __builtin_bit_cast(unsigned, f);
    u += 0x7fffu + ((u >> 16) & 1u);          // RNE
    return (unsigned short)(u >> 16);
}
__device__ __forceinline__ float bf2f(unsigned short h) {
    unsigned u = ((unsigned)h) << 16;
    return __builtin_bit_cast(float, u);
}
__device__ __forceinline__ void gl_lds16(const void* g, void* l) {
    __builtin_amdgcn_global_load_lds(
        (__attribute__((address_space(1))) void*)g,
        (__attribute__((address_space(3))) void*)l, 16, 0, 0);
}

// ---------------------------------------------------------------------------
// pack ew2/ew3/nw2: dst[(kb*512+c)*8+j] = bf16(src[(kb*8+j)*512+c])
__global__ void pack_w(const float* __restrict__ src, unsigned short* __restrict__ dst, int n)
{
    int idx = blockIdx.x * 256 + threadIdx.x;
    if (idx >= n) return;
    int j = idx & 7, c = (idx >> 3) & 511, kb = idx >> 12;
    dst[idx] = f2bf(src[(size_t)(kb * 8 + j) * 512 + c]);
}

// nw1 packed with row remap: k<36 -> k ; 36..63 -> zero ; k>=64 -> k-28
__global__ void pack_nw1(const float* __restrict__ src, unsigned short* __restrict__ dst)
{
    int idx = blockIdx.x * 256 + threadIdx.x;
    if (idx >= 576 * 512) return;
    int j = idx & 7, c = (idx >> 3) & 511, kb = idx >> 12;
    int k = kb * 8 + j;
    int sk = (k < 36) ? k : (k < 64 ? -1 : k - 28);
    dst[idx] = f2bf(sk < 0 ? 0.f : src[(size_t)sk * 512 + c]);
}

// ew1p [32,1024]: cols 0..511 from ew1[0:32], cols 512..1023 from ew1[32:64]
__global__ void pack_ew1(const float* __restrict__ src, unsigned short* __restrict__ dst)
{
    int idx = blockIdx.x * 256 + threadIdx.x;
    if (idx >= 32 * 1024) return;
    int j = idx & 7, c = (idx >> 3) & 1023, kb = idx >> 13;
    int k = kb * 8 + j;
    float v = (c < 512) ? src[(size_t)k * 512 + c] : src[(size_t)(32 + k) * 512 + (c - 512)];
    dst[idx] = f2bf(v);
}

// ---------------------------------------------------------------------------
// PQ = X @ ew1p : M=32/block, N split in halves of 512. 256 thr = 4 waves.
__global__ __launch_bounds__(256) void pq_mfma(
    const float* __restrict__ X, const unsigned short* __restrict__ ew1p,
    unsigned short* __restrict__ PQ)
{
    const int t = threadIdx.x, w = t >> 6, lane = t & 63;
    const int lr = lane & 15, lg = lane >> 4;
    const int rb = blockIdx.x * 32;
    const int half = blockIdx.y;

    bf16x8 a[2];
#pragma unroll
    for (int m = 0; m < 2; ++m) {
        const float* s = X + (size_t)(rb + m * 16 + lr) * 32 + lg * 8;
        float4 x0 = *(const float4*)s, x1 = *(const float4*)(s + 4);
        u16x8 u;
        u[0] = f2bf(x0.x); u[1] = f2bf(x0.y); u[2] = f2bf(x0.z); u[3] = f2bf(x0.w);
        u[4] = f2bf(x1.x); u[5] = f2bf(x1.y); u[6] = f2bf(x1.z); u[7] = f2bf(x1.w);
        a[m] = __builtin_bit_cast(bf16x8, u);
    }
    f32x4 acc[2][8] = {};
#pragma unroll
    for (int nt = 0; nt < 8; ++nt) {
        int col = half * 512 + w * 128 + nt * 16 + lr;
        bf16x8 b = __builtin_bit_cast(bf16x8, *(const u16x8*)(ew1p + ((size_t)lg * 1024 + col) * 8));
        acc[0][nt] = __builtin_amdgcn_mfma_f32_16x16x32_bf16(a[0], b, acc[0][nt], 0, 0, 0);
        acc[1][nt] = __builtin_amdgcn_mfma_f32_16x16x32_bf16(a[1], b, acc[1][nt], 0, 0, 0);
    }
#pragma unroll
    for (int m = 0; m < 2; ++m)
#pragma unroll
        for (int nt = 0; nt < 8; ++nt)
#pragma unroll
            for (int reg = 0; reg < 4; ++reg)
                PQ[(size_t)(rb + m * 16 + lg * 4 + reg) * 1024 + half * 512 + w * 128 + nt * 16 + lr]
                    = f2bf(acc[m][nt][reg]);
}

// ---------------------------------------------------------------------------
// Edge kernel v4: one graph/block, 1024 thr = 16 waves (wm=w>>3, wn=w&7).
// Tile 96x512, BK=32, B double-buffered via global_load_lds, A (h1) built from
// regs prefetched one K-step ahead, stride-40 u16 LDS rows (bank-spread).
__global__ __launch_bounds__(1024) void edge_v4(
    const unsigned short* __restrict__ PQ, const float* __restrict__ eb1,
    const unsigned short* __restrict__ ew2p, const float* __restrict__ eb2,
    const float* __restrict__ eg, const float* __restrict__ ebt,
    unsigned short* __restrict__ S)
{
    __shared__ __align__(16) unsigned short Bsh[2][16384];  // 2 x 32KB
    __shared__ __align__(16) unsigned short Ash[2][3840];   // 2 x 7.5KB (96 rows x stride 40)
    __shared__ float sums[96], ssums[96];

    const int t = threadIdx.x;
    const int w = t >> 6, lane = t & 63;
    const int lr = lane & 15, lg = lane >> 4;
    const int wm = w >> 3, wn = w & 7;
    const int g = blockIdx.x;

    if (t < 96) { sums[t] = 0.f; ssums[t] = 0.f; }

    // A-build task: 384 tasks = 16 waves x 24 lanes. row = edge 0..95, kg = k-subgroup.
    const int tau = w * 24 + lane;
    const bool abuild = (lane < 24);
    const int arow = tau >> 2, akg = tau & 3;
    const bool avalid = abuild && (arow < 90);
    int ai = 0, aj = 1;
    if (avalid) { ai = arow / 9; int jj = arow - ai * 9; aj = jj + (jj >= ai); }
    const unsigned short* pqP = PQ + ((size_t)(g * KOBJ + ai)) * 1024 + akg * 8;
    const unsigned short* pqQ = PQ + ((size_t)(g * KOBJ + aj)) * 1024 + 512 + akg * 8;
    const float* ebb = eb1 + akg * 8;

    u16x8 rp = (u16x8)(unsigned short)0, rq = (u16x8)(unsigned short)0;
    float4 re0 = {}, re1 = {};

    auto fillB = [&](int kc, int buf) {
        const unsigned short* src = ew2p + (size_t)kc * 16384;
        char* db = (char*)&Bsh[buf][0];
        gl_lds16(src + ((size_t)t) * 8,          db + w * 1024);
        gl_lds16(src + ((size_t)(1024 + t)) * 8, db + 16384 + w * 1024);
    };
    auto buildA = [&](int buf) {
        if (abuild) {
            u16x8 o;
            float ev[8] = {re0.x, re0.y, re0.z, re0.w, re1.x, re1.y, re1.z, re1.w};
#pragma unroll
            for (int q = 0; q < 8; ++q) {
                float v = bf2f(rp[q]) + bf2f(rq[q]) + ev[q];
                o[q] = f2bf(fmaxf(v, 0.f));
            }
            if (!avalid) o = (u16x8)(unsigned short)0;
            *(u16x8*)(&Ash[buf][arow * 40 + akg * 8]) = o;
        }
    };
    auto loadPQ = [&](int kc) {
        if (avalid) {
            rp = *(const u16x8*)(pqP + kc * 32);
            rq = *(const u16x8*)(pqQ + kc * 32);
            re0 = *(const float4*)(ebb + kc * 32);
            re1 = *(const float4*)(ebb + kc * 32 + 4);
        }
    };

    f32x4 acc[3][4] = {};

    // prologue
    loadPQ(0);
    buildA(0);
    loadPQ(1);
    fillB(0, 0);

    int cur = 0;
    for (int kc = 0; kc < 16; ++kc) {
        __syncthreads();              // drains prev fills (overlapped w/ compute)
        if (kc < 15) {
            fillB(kc + 1, cur ^ 1);
            buildA(cur ^ 1);          // uses regs prefetched for kc+1
            if (kc < 14) loadPQ(kc + 2);
        }
        const unsigned short* Ab = &Ash[cur][0];
        const unsigned short* Bb = &Bsh[cur][0];
        bf16x8 a0 = *(const bf16x8*)(Ab + (wm * 48 +  0 + lr) * 40 + lg * 8);
        bf16x8 a1 = *(const bf16x8*)(Ab + (wm * 48 + 16 + lr) * 40 + lg * 8);
        bf16x8 a2 = *(const bf16x8*)(Ab + (wm * 48 + 32 + lr) * 40 + lg * 8);
#pragma unroll
        for (int nt = 0; nt < 4; ++nt) {
            bf16x8 b = *(const bf16x8*)(Bb + ((size_t)(lg * 512) + wn * 64 + nt * 16 + lr) * 8);
            acc[0][nt] = __builtin_amdgcn_mfma_f32_16x16x32_bf16(a0, b, acc[0][nt], 0, 0, 0);
            acc[1][nt] = __builtin_amdgcn_mfma_f32_16x16x32_bf16(a1, b, acc[1][nt], 0, 0, 0);
            acc[2][nt] = __builtin_amdgcn_mfma_f32_16x16x32_bf16(a2, b, acc[2][nt], 0, 0, 0);
        }
        cur ^= 1;
    }

    // epilogue: bias, LN stats, normalize, relu, aggregate per node
    __syncthreads();
    float* Sl = (float*)&Bsh[0][0];   // 10x512 f32 aliased into B buffers
    for (int i2 = t; i2 < KOBJ * 512; i2 += 1024) Sl[i2] = 0.f;

    float b2[4], gv[4], bv2[4];
#pragma unroll
    for (int nt = 0; nt < 4; ++nt) {
        int c = wn * 64 + nt * 16 + lr;
        b2[nt] = eb2[c]; gv[nt] = eg[c]; bv2[nt] = ebt[c];
    }
#pragma unroll
    for (int m = 0; m < 3; ++m)
#pragma unroll
        for (int reg = 0; reg < 4; ++reg) {
            float s = 0.f, ss = 0.f;
#pragma unroll
            for (int nt = 0; nt < 4; ++nt) {
                float v = acc[m][nt][reg] + b2[nt];
                acc[m][nt][reg] = v;
                s += v; ss += v * v;
            }
#pragma unroll
            for (int msk = 1; msk < 16; msk <<= 1) {
                s  += __shfl_xor(s,  msk, 64);
                ss += __shfl_xor(ss, msk, 64);
            }
            if (lr == 0) {
                int row = wm * 48 + m * 16 + lg * 4 + reg;
                atomicAdd(&sums[row], s);
                atomicAdd(&ssums[row], ss);
            }
        }
    __syncthreads();
#pragma unroll
    for (int m = 0; m < 3; ++m)
#pragma unroll
        for (int reg = 0; reg < 4; ++reg) {
            int row = wm * 48 + m * 16 + lg * 4 + reg;
            float mean = sums[row] * (1.f / 512.f);
            float var  = ssums[row] * (1.f / 512.f) - mean * mean;
            float inv  = rsqrtf(var + LN_EPS);
            if (row < 90) {
                int node = row / 9;
#pragma unroll
                for (int nt = 0; nt < 4; ++nt) {
                    float h = fmaxf((acc[m][nt][reg] - mean) * inv * gv[nt] + bv2[nt], 0.f);
                    atomicAdd(&Sl[node * 512 + wn * 64 + nt * 16 + lr], h);
                }
            }
        }
    __syncthreads();
    for (int i2 = t; i2 < KOBJ * 512; i2 += 1024)
        S[(size_t)g * (KOBJ * 512) + i2] = f2bf(Sl[i2]);
}

// ---------------------------------------------------------------------------
// Node GEMM v4: M=32/block, N=512, BK=64, A+B staged via global_load_lds.
// 512 thr = 8 waves, wave w owns cols w*64 (4 n-tiles), rows 32 (2 m-tiles).
// MODE 0: +bias*9 -> bf16. MODE 1: +bias, relu -> bf16. MODE 2: +bias, LN, relu -> bf16.
template<int MODE, int NK, int LDA>
__global__ __launch_bounds__(512, 4) void node_v4(
    const unsigned short* __restrict__ A, const unsigned short* __restrict__ Wp,
    const float* __restrict__ bias, const float* __restrict__ gamma,
    const float* __restrict__ beta, unsigned short* __restrict__ outb,
    int ldo, int ocol)
{
    __shared__ __align__(16) unsigned short Bt[32768];   // 64KB
    __shared__ __align__(16) unsigned short At[2048];    // 4KB, XOR-swizzled
    __shared__ float sums[32], ssums[32];
    const int t = threadIdx.x, w = t >> 6, lane = t & 63;
    const int lr = lane & 15, lg = lane >> 4;
    const int rb = blockIdx.x * 32;
    if (MODE == 2 && t < 32) { sums[t] = 0.f; ssums[t] = 0.f; }

    f32x4 acc[2][4] = {};
    for (int kc = 0; kc < NK; ++kc) {
        __syncthreads();
#pragma unroll
        for (int R = 0; R < 8; ++R)
            gl_lds16(Wp + ((size_t)kc * 4096 + R * 512 + t) * 8,
                     (char*)Bt + R * 8192 + w * 1024);
        if (w < 4) {   // A: 32 rows x 64 k = 4KB; source col XOR-swizzled per row
            int row = t >> 3, cp = t & 7;
            int scol = cp ^ (row & 7);
            gl_lds16(A + (size_t)(rb + row) * LDA + kc * 64 + scol * 8,
                     (char*)At + (t & ~63) * 16);
        }
        __syncthreads();
#pragma unroll
        for (int ks = 0; ks < 2; ++ks) {
            int kidx = ks * 4 + lg;
            bf16x8 a0 = *(const bf16x8*)(At + ( 0 + lr) * 64 + (kidx ^ (lr & 7)) * 8);
            bf16x8 a1 = *(const bf16x8*)(At + (16 + lr) * 64 + (kidx ^ (lr & 7)) * 8);
#pragma unroll
            for (int nt = 0; nt < 4; ++nt) {
                bf16x8 b = *(const bf16x8*)(Bt + ((size_t)kidx * 512 + w * 64 + nt * 16 + lr) * 8);
                acc[0][nt] = __builtin_amdgcn_mfma_f32_16x16x32_bf16(a0, b, acc[0][nt], 0, 0, 0);
                acc[1][nt] = __builtin_amdgcn_mfma_f32_16x16x32_bf16(a1, b, acc[1][nt], 0, 0, 0);
            }
        }
    }

    float bv[4];
#pragma unroll
    for (int nt = 0; nt < 4; ++nt)
        bv[nt] = bias[w * 64 + nt * 16 + lr] * (MODE == 0 ? 9.f : 1.f);

    if constexpr (MODE != 2) {
#pragma unroll
        for (int m = 0; m < 2; ++m)
#pragma unroll
            for (int reg = 0; reg < 4; ++reg)
#pragma unroll
                for (int nt = 0; nt < 4; ++nt) {
                    float v = acc[m][nt][reg] + bv[nt];
                    if constexpr (MODE == 1) v = fmaxf(v, 0.f);
                    outb[(size_t)(rb + m * 16 + lg * 4 + reg) * ldo + ocol + w * 64 + nt * 16 + lr] = f2bf(v);
                }
    } else {
        float gv[4], be[4];
#pragma unroll
        for (int nt = 0; nt < 4; ++nt) {
            int c = w * 64 + nt * 16 + lr;
            gv[nt] = gamma[c]; be[nt] = beta[c];
        }
#pragma unroll
        for (int m = 0; m < 2; ++m)
#pragma unroll
            for (int reg = 0; reg < 4; ++reg) {
                float s = 0.f, ss = 0.f;
#pragma unroll
                for (int nt = 0; nt < 4; ++nt) {
                    float v = acc[m][nt][reg] + bv[nt];
                    acc[m][nt][reg] = v;
                    s += v; ss += v * v;
                }
#pragma unroll
                for (int msk = 1; msk < 16; msk <<= 1) {
                    s  += __shfl_xor(s,  msk, 64);
                    ss += __shfl_xor(ss, msk, 64);
                }
                if (lr == 0) {
                    atomicAdd(&sums [m * 16 + lg * 4 + reg], s);
                    atomicAdd(&ssums[m * 16 + lg * 4 + reg], ss);
                }
            }
        __syncthreads();
#pragma unroll
        for (int m = 0; m < 2; ++m)
#pragma unroll
            for (int reg = 0; reg < 4; ++reg) {
                int rl = m * 16 + lg * 4 + reg;
                float mean = sums[rl] * (1.f / 512.f);
                float var  = ssums[rl] * (1.f / 512.f) - mean * mean;
                float inv  = rsqrtf(var + LN_EPS);
#pragma unroll
                for (int nt = 0; nt < 4; ++nt) {
                    float v = fmaxf((acc[m][nt][reg] - mean) * inv * gv[nt] + be[nt], 0.f);
                    outb[(size_t)(rb + rl) * ldo + w * 64 + nt * 16 + lr] = f2bf(v);
                }
            }
    }
}

// ---------------------------------------------------------------------------
// NIN[:,0:64] = [X(32) | onehot(4) | zeros(28)]  (bf16, ld 576)
__global__ void concat64(const float* __restrict__ X, const int* __restrict__ act,
                         unsigned short* __restrict__ NIN)
{
    int idx = blockIdx.x * 256 + threadIdx.x;
    if (idx >= NNODES * 64) return;
    int r = idx >> 6, c = idx & 63;
    float v = 0.f;
    if (c < DIN) v = X[(size_t)r * DIN + c];
    else if (c < DIN + 4) v = (act[r / KOBJ] == (c - DIN)) ? 1.f : 0.f;
    NIN[(size_t)r * 576 + c] = f2bf(v);
}

// ---------------------------------------------------------------------------
// out[10240,32] = H2(bf16) @ nw3 + nb3 (f32 out)
__global__ __launch_bounds__(256) void out_v4(
    const unsigned short* __restrict__ H2, const float* __restrict__ W3,
    const float* __restrict__ b3, float* __restrict__ out)
{
    int t = threadIdx.x;
    int r = blockIdx.x * 8 + (t >> 5);
    int c = t & 31;
    const unsigned short* h = H2 + (size_t)r * HID;
    float acc = 0.f;
#pragma unroll 8
    for (int k8 = 0; k8 < 64; ++k8) {
        u16x8 hv = *(const u16x8*)(h + k8 * 8);
#pragma unroll
        for (int q = 0; q < 8; ++q)
            acc = fmaf(bf2f(hv[q]), W3[(k8 * 8 + q) * DIN + c], acc);
    }
    out[(size_t)r * DIN + c] = acc + b3[c];
}

// ---------------------------------------------------------------------------
extern "C" void kernel_launch(void* const* d_in, const int* in_sizes, int n_in,
                              void* d_out, int out_size, void* d_ws, size_t ws_size,
                              hipStream_t stream)
{
    const float* states = (const float*)d_in[0];
    const int*   action = (const int*)d_in[1];
    const float* ew1 = (const float*)d_in[2];
    const float* eb1 = (const float*)d_in[3];
    const float* ew2 = (const float*)d_in[4];
    const float* eb2 = (const float*)d_in[5];
    const float* eg  = (const float*)d_in[6];
    const float* ebt = (const float*)d_in[7];
    const float* ew3 = (const float*)d_in[8];
    const float* eb3 = (const float*)d_in[9];
    const float* nw1 = (const float*)d_in[10];
    const float* nb1 = (const float*)d_in[11];
    const float* nw2 = (const float*)d_in[12];
    const float* nb2 = (const float*)d_in[13];
    const float* ng  = (const float*)d_in[14];
    const float* nbt = (const float*)d_in[15];
    const float* nw3 = (const float*)d_in[16];
    const float* nb3 = (const float*)d_in[17];

    char* wsb = (char*)d_ws;
    unsigned short* PQ   = (unsigned short*)(wsb);               // 10240x1024 bf16
    unsigned short* S    = (unsigned short*)(wsb + 20971520);    // 10240x512
    unsigned short* NIN  = (unsigned short*)(wsb + 31457280);    // 10240x576
    unsigned short* Hh   = (unsigned short*)(wsb + 43253760);    // 10240x512
    unsigned short* H2   = (unsigned short*)(wsb + 53739520);    // 10240x512
    unsigned short* ew1p = (unsigned short*)(wsb + 64225280);    // 32x1024
    unsigned short* ew2p = (unsigned short*)(wsb + 64290816);    // 512x512
    unsigned short* ew3p = (unsigned short*)(wsb + 64815104);
    unsigned short* nw2p = (unsigned short*)(wsb + 65339392);
    unsigned short* nw1p = (unsigned short*)(wsb + 65863680);    // 576x512
    float* out = (float*)d_out;

    hipLaunchKernelGGL(pack_ew1, dim3(128), dim3(256), 0, stream, ew1, ew1p);
    hipLaunchKernelGGL(pack_w, dim3(1024), dim3(256), 0, stream, ew2, ew2p, 512 * 512);
    hipLaunchKernelGGL(pack_w, dim3(1024), dim3(256), 0, stream, ew3, ew3p, 512 * 512);
    hipLaunchKernelGGL(pack_w, dim3(1024), dim3(256), 0, stream, nw2, nw2p, 512 * 512);
    hipLaunchKernelGGL(pack_nw1, dim3(1152), dim3(256), 0, stream, nw1, nw1p);

    hipLaunchKernelGGL(pq_mfma, dim3(320, 2), dim3(256), 0, stream, states, ew1p, PQ);
    hipLaunchKernelGGL(edge_v4, dim3(NGRAPH), dim3(1024), 0, stream,
                       PQ, eb1, ew2p, eb2, eg, ebt, S);
    hipLaunchKernelGGL((node_v4<0, 8, 512>), dim3(320), dim3(512), 0, stream,
                       S, ew3p, eb3, nullptr, nullptr, NIN, 576, 64);
    hipLaunchKernelGGL(concat64, dim3(2560), dim3(256), 0, stream, states, action, NIN);
    hipLaunchKernelGGL((node_v4<1, 9, 576>), dim3(320), dim3(512), 0, stream,
                       NIN, nw1p, nb1, nullptr, nullptr, Hh, 512, 0);
    hipLaunchKernelGGL((node_v4<2, 8, 512>), dim3(320), dim3(512), 0, stream,
                       Hh, nw2p, nb2, ng, nbt, H2, 512, 0);
    hipLaunchKernelGGL(out_v4, dim3(NNODES / 8), dim3(256), 0, stream,
                       H2, nw3, nb3, out);
}

// Round 5
// 260.197 us; speedup vs baseline: 6.3638x; 1.6799x over previous
//
#include <hip/hip_runtime.h>

// TransitionGNN forward, v5: decoupled edge path (h1 materialize -> clean GEMM -> segsum).
// B=1024 graphs, K=10 objects, D=32, H=512. Nodes N=10240, 90 edges/graph.
// Edge rows processed in 4 chunks of 256 graphs (23040 edge rows) to bound workspace.

#define HID 512
#define DIN 32
#define KOBJ 10
#define NGRAPH 1024
#define NNODES (NGRAPH*KOBJ)
#define LN_EPS 1e-5f

#define NG_C   256            // graphs per chunk
#define ROWS_C (NG_C*90)      // 23040 edge rows per chunk
#define NODES_C (NG_C*KOBJ)   // 2560 nodes per chunk

typedef __bf16 bf16x8 __attribute__((ext_vector_type(8)));
typedef unsigned short u16x8 __attribute__((ext_vector_type(8)));
typedef float f32x4 __attribute__((ext_vector_type(4)));

__device__ __forceinline__ unsigned short f2bf(float f) {
    unsigned u = __builtin_bit_cast(unsigned, f);
    u += 0x7fffu + ((u >> 16) & 1u);          // RNE
    return (unsigned short)(u >> 16);
}
__device__ __forceinline__ float bf2f(unsigned short h) {
    unsigned u = ((unsigned)h) << 16;
    return __builtin_bit_cast(float, u);
}
__device__ __forceinline__ void gl_lds16(const void* g, void* l) {
    __builtin_amdgcn_global_load_lds(
        (__attribute__((address_space(1))) void*)g,
        (__attribute__((address_space(3))) void*)l, 16, 0, 0);
}

// ---------------------------------------------------------------------------
// pack ew2/ew3/nw2: dst[(kb*512+c)*8+j] = bf16(src[(kb*8+j)*512+c])
__global__ void pack_w(const float* __restrict__ src, unsigned short* __restrict__ dst, int n)
{
    int idx = blockIdx.x * 256 + threadIdx.x;
    if (idx >= n) return;
    int j = idx & 7, c = (idx >> 3) & 511, kb = idx >> 12;
    dst[idx] = f2bf(src[(size_t)(kb * 8 + j) * 512 + c]);
}

// nw1 packed with row remap: k<36 -> k ; 36..63 -> zero ; k>=64 -> k-28
__global__ void pack_nw1(const float* __restrict__ src, unsigned short* __restrict__ dst)
{
    int idx = blockIdx.x * 256 + threadIdx.x;
    if (idx >= 576 * 512) return;
    int j = idx & 7, c = (idx >> 3) & 511, kb = idx >> 12;
    int k = kb * 8 + j;
    int sk = (k < 36) ? k : (k < 64 ? -1 : k - 28);
    dst[idx] = f2bf(sk < 0 ? 0.f : src[(size_t)sk * 512 + c]);
}

// ew1p [32,1024]: cols 0..511 from ew1[0:32], cols 512..1023 from ew1[32:64]
__global__ void pack_ew1(const float* __restrict__ src, unsigned short* __restrict__ dst)
{
    int idx = blockIdx.x * 256 + threadIdx.x;
    if (idx >= 32 * 1024) return;
    int j = idx & 7, c = (idx >> 3) & 1023, kb = idx >> 13;
    int k = kb * 8 + j;
    float v = (c < 512) ? src[(size_t)k * 512 + c] : src[(size_t)(32 + k) * 512 + (c - 512)];
    dst[idx] = f2bf(v);
}

// ---------------------------------------------------------------------------
// PQ = X @ ew1p : M=32/block, N split in halves of 512. 256 thr = 4 waves.
__global__ __launch_bounds__(256) void pq_mfma(
    const float* __restrict__ X, const unsigned short* __restrict__ ew1p,
    unsigned short* __restrict__ PQ)
{
    const int t = threadIdx.x, w = t >> 6, lane = t & 63;
    const int lr = lane & 15, lg = lane >> 4;
    const int rb = blockIdx.x * 32;
    const int half = blockIdx.y;

    bf16x8 a[2];
#pragma unroll
    for (int m = 0; m < 2; ++m) {
        const float* s = X + (size_t)(rb + m * 16 + lr) * 32 + lg * 8;
        float4 x0 = *(const float4*)s, x1 = *(const float4*)(s + 4);
        u16x8 u;
        u[0] = f2bf(x0.x); u[1] = f2bf(x0.y); u[2] = f2bf(x0.z); u[3] = f2bf(x0.w);
        u[4] = f2bf(x1.x); u[5] = f2bf(x1.y); u[6] = f2bf(x1.z); u[7] = f2bf(x1.w);
        a[m] = __builtin_bit_cast(bf16x8, u);
    }
    f32x4 acc[2][8] = {};
#pragma unroll
    for (int nt = 0; nt < 8; ++nt) {
        int col = half * 512 + w * 128 + nt * 16 + lr;
        bf16x8 b = __builtin_bit_cast(bf16x8, *(const u16x8*)(ew1p + ((size_t)lg * 1024 + col) * 8));
        acc[0][nt] = __builtin_amdgcn_mfma_f32_16x16x32_bf16(a[0], b, acc[0][nt], 0, 0, 0);
        acc[1][nt] = __builtin_amdgcn_mfma_f32_16x16x32_bf16(a[1], b, acc[1][nt], 0, 0, 0);
    }
#pragma unroll
    for (int m = 0; m < 2; ++m)
#pragma unroll
        for (int nt = 0; nt < 8; ++nt)
#pragma unroll
            for (int reg = 0; reg < 4; ++reg)
                PQ[(size_t)(rb + m * 16 + lg * 4 + reg) * 1024 + half * 512 + w * 128 + nt * 16 + lr]
                    = f2bf(acc[m][nt][reg]);
}

// ---------------------------------------------------------------------------
// h1[r, c] = relu(P[i(r)] + Q[j(r)] + eb1)[c]   (bf16, one chunk of 23040 rows)
__global__ __launch_bounds__(256) void h1_build(
    const unsigned short* __restrict__ PQ, const float* __restrict__ eb1,
    unsigned short* __restrict__ h1, int gbase)
{
    int idx = blockIdx.x * 256 + threadIdx.x;       // < ROWS_C * 64
    int r = idx >> 6, c8 = idx & 63;
    int gl = r / 90, le = r - gl * 90;
    int i = le / 9, jj = le - i * 9;
    int j = jj + (jj >= i);
    const unsigned short* p = PQ + ((size_t)((gbase + gl) * KOBJ + i)) * 1024 + c8 * 8;
    const unsigned short* q = PQ + ((size_t)((gbase + gl) * KOBJ + j)) * 1024 + 512 + c8 * 8;
    u16x8 up = *(const u16x8*)p, uq = *(const u16x8*)q;
    float4 e0 = *(const float4*)(eb1 + c8 * 8), e1 = *(const float4*)(eb1 + c8 * 8 + 4);
    float ev[8] = {e0.x, e0.y, e0.z, e0.w, e1.x, e1.y, e1.z, e1.w};
    u16x8 o;
#pragma unroll
    for (int k = 0; k < 8; ++k)
        o[k] = f2bf(fmaxf(bf2f(up[k]) + bf2f(uq[k]) + ev[k], 0.f));
    *(u16x8*)(h1 + (size_t)r * 512 + c8 * 8) = o;
}

// ---------------------------------------------------------------------------
// Edge GEMM v5: pure m97-style. C[64 x 512] = h1-tile @ ew2 (+eb2, LN, *eg+ebt, relu).
// 512 thr = 8 waves (2x4); wave tile 32x128. BK=32, A+B via global_load_lds, dbuf.
__global__ __launch_bounds__(512, 4) void edge_gemm(
    const unsigned short* __restrict__ h1, const unsigned short* __restrict__ ew2p,
    const float* __restrict__ eb2, const float* __restrict__ eg,
    const float* __restrict__ ebt, unsigned short* __restrict__ H2e)
{
    __shared__ __align__(16) unsigned short Bsh[2][16384];  // 2 x 32KB  [lg 0..3][col 512][8]
    __shared__ __align__(16) unsigned short Ash[2][2048];   // 2 x 4KB   [row 64][kg 4][8]
    __shared__ float sums[64], ssums[64];

    const int t = threadIdx.x, w = t >> 6, lane = t & 63;
    const int lr = lane & 15, lg = lane >> 4;
    const int wr = w >> 2, wc = w & 3;
    const int rb = blockIdx.x * 64;

    if (t < 64) { sums[t] = 0.f; ssums[t] = 0.f; }

    auto fill = [&](int kc, int buf) {
        char* Bb = (char*)&Bsh[buf][0];
#pragma unroll
        for (int R = 0; R < 4; ++R)
            gl_lds16(ew2p + (size_t)kc * 16384 + R * 4096 + t * 8, Bb + R * 8192 + w * 1024);
        if (w < 4)
            gl_lds16(h1 + (size_t)(rb + (t >> 2)) * 512 + kc * 32 + (t & 3) * 8,
                     (char*)&Ash[buf][0] + w * 1024);
    };

    f32x4 acc[2][8] = {};
    fill(0, 0);
    __syncthreads();
    int cur = 0;
    for (int kc = 0; kc < 16; ++kc) {
        if (kc < 15) fill(kc + 1, cur ^ 1);
        const unsigned short* Ab = &Ash[cur][0];
        const unsigned short* Bb = &Bsh[cur][0];
        bf16x8 a0 = *(const bf16x8*)(Ab + ((wr * 32 + lr) * 4 + lg) * 8);
        bf16x8 a1 = *(const bf16x8*)(Ab + ((wr * 32 + 16 + lr) * 4 + lg) * 8);
#pragma unroll
        for (int nt = 0; nt < 8; ++nt) {
            bf16x8 b = *(const bf16x8*)(Bb + ((size_t)lg * 512 + wc * 128 + nt * 16 + lr) * 8);
            acc[0][nt] = __builtin_amdgcn_mfma_f32_16x16x32_bf16(a0, b, acc[0][nt], 0, 0, 0);
            acc[1][nt] = __builtin_amdgcn_mfma_f32_16x16x32_bf16(a1, b, acc[1][nt], 0, 0, 0);
        }
        __syncthreads();
        cur ^= 1;
    }

    // epilogue: +eb2, LN over the full 512-wide row (cross-wave via LDS), *eg+ebt, relu
    float b2[8], gv[8], bb[8];
#pragma unroll
    for (int nt = 0; nt < 8; ++nt) {
        int c = wc * 128 + nt * 16 + lr;
        b2[nt] = eb2[c]; gv[nt] = eg[c]; bb[nt] = ebt[c];
    }
#pragma unroll
    for (int m = 0; m < 2; ++m)
#pragma unroll
        for (int reg = 0; reg < 4; ++reg) {
            float s = 0.f, ss = 0.f;
#pragma unroll
            for (int nt = 0; nt < 8; ++nt) {
                float v = acc[m][nt][reg] + b2[nt];
                acc[m][nt][reg] = v;
                s += v; ss += v * v;
            }
#pragma unroll
            for (int msk = 1; msk < 16; msk <<= 1) {
                s  += __shfl_xor(s,  msk, 64);
                ss += __shfl_xor(ss, msk, 64);
            }
            if (lr == 0) {
                int rl = wr * 32 + m * 16 + lg * 4 + reg;
                atomicAdd(&sums[rl], s);
                atomicAdd(&ssums[rl], ss);
            }
        }
    __syncthreads();
#pragma unroll
    for (int m = 0; m < 2; ++m)
#pragma unroll
        for (int reg = 0; reg < 4; ++reg) {
            int rl = wr * 32 + m * 16 + lg * 4 + reg;
            float mean = sums[rl] * (1.f / 512.f);
            float var  = ssums[rl] * (1.f / 512.f) - mean * mean;
            float inv  = rsqrtf(var + LN_EPS);
#pragma unroll
            for (int nt = 0; nt < 8; ++nt) {
                float h = fmaxf((acc[m][nt][reg] - mean) * inv * gv[nt] + bb[nt], 0.f);
                H2e[(size_t)(rb + rl) * 512 + wc * 128 + nt * 16 + lr] = f2bf(h);
            }
        }
}

// ---------------------------------------------------------------------------
// S[nbase+n] = sum_{k=0..8} H2e[n*9+k]   (bf16 in/out, f32 accumulate)
__global__ __launch_bounds__(256) void segsum(
    const unsigned short* __restrict__ H2e, unsigned short* __restrict__ S, int nbase)
{
    int idx = blockIdx.x * 256 + threadIdx.x;       // < NODES_C * 64
    int n = idx >> 6, c8 = idx & 63;
    float acc[8] = {};
#pragma unroll
    for (int k = 0; k < 9; ++k) {
        u16x8 v = *(const u16x8*)(H2e + ((size_t)(n * 9 + k)) * 512 + c8 * 8);
#pragma unroll
        for (int q = 0; q < 8; ++q) acc[q] += bf2f(v[q]);
    }
    u16x8 o;
#pragma unroll
    for (int q = 0; q < 8; ++q) o[q] = f2bf(acc[q]);
    *(u16x8*)(S + ((size_t)(nbase + n)) * 512 + c8 * 8) = o;
}

// ---------------------------------------------------------------------------
// Node MFMA GEMM (unchanged from R4): M=32/block, N=512, BK=64, gl_lds staged.
template<int MODE, int NK, int LDA>
__global__ __launch_bounds__(512, 4) void node_v4(
    const unsigned short* __restrict__ A, const unsigned short* __restrict__ Wp,
    const float* __restrict__ bias, const float* __restrict__ gamma,
    const float* __restrict__ beta, unsigned short* __restrict__ outb,
    int ldo, int ocol)
{
    __shared__ __align__(16) unsigned short Bt[32768];   // 64KB
    __shared__ __align__(16) unsigned short At[2048];    // 4KB, XOR-swizzled
    __shared__ float sums[32], ssums[32];
    const int t = threadIdx.x, w = t >> 6, lane = t & 63;
    const int lr = lane & 15, lg = lane >> 4;
    const int rb = blockIdx.x * 32;
    if (MODE == 2 && t < 32) { sums[t] = 0.f; ssums[t] = 0.f; }

    f32x4 acc[2][4] = {};
    for (int kc = 0; kc < NK; ++kc) {
        __syncthreads();
#pragma unroll
        for (int R = 0; R < 8; ++R)
            gl_lds16(Wp + ((size_t)kc * 4096 + R * 512 + t) * 8,
                     (char*)Bt + R * 8192 + w * 1024);
        if (w < 4) {
            int row = t >> 3, cp = t & 7;
            int scol = cp ^ (row & 7);
            gl_lds16(A + (size_t)(rb + row) * LDA + kc * 64 + scol * 8,
                     (char*)At + (t & ~63) * 16);
        }
        __syncthreads();
#pragma unroll
        for (int ks = 0; ks < 2; ++ks) {
            int kidx = ks * 4 + lg;
            bf16x8 a0 = *(const bf16x8*)(At + ( 0 + lr) * 64 + (kidx ^ (lr & 7)) * 8);
            bf16x8 a1 = *(const bf16x8*)(At + (16 + lr) * 64 + (kidx ^ (lr & 7)) * 8);
#pragma unroll
            for (int nt = 0; nt < 4; ++nt) {
                bf16x8 b = *(const bf16x8*)(Bt + ((size_t)kidx * 512 + w * 64 + nt * 16 + lr) * 8);
                acc[0][nt] = __builtin_amdgcn_mfma_f32_16x16x32_bf16(a0, b, acc[0][nt], 0, 0, 0);
                acc[1][nt] = __builtin_amdgcn_mfma_f32_16x16x32_bf16(a1, b, acc[1][nt], 0, 0, 0);
            }
        }
    }

    float bv[4];
#pragma unroll
    for (int nt = 0; nt < 4; ++nt)
        bv[nt] = bias[w * 64 + nt * 16 + lr] * (MODE == 0 ? 9.f : 1.f);

    if constexpr (MODE != 2) {
#pragma unroll
        for (int m = 0; m < 2; ++m)
#pragma unroll
            for (int reg = 0; reg < 4; ++reg)
#pragma unroll
                for (int nt = 0; nt < 4; ++nt) {
                    float v = acc[m][nt][reg] + bv[nt];
                    if constexpr (MODE == 1) v = fmaxf(v, 0.f);
                    outb[(size_t)(rb + m * 16 + lg * 4 + reg) * ldo + ocol + w * 64 + nt * 16 + lr] = f2bf(v);
                }
    } else {
        float gv[4], be[4];
#pragma unroll
        for (int nt = 0; nt < 4; ++nt) {
            int c = w * 64 + nt * 16 + lr;
            gv[nt] = gamma[c]; be[nt] = beta[c];
        }
#pragma unroll
        for (int m = 0; m < 2; ++m)
#pragma unroll
            for (int reg = 0; reg < 4; ++reg) {
                float s = 0.f, ss = 0.f;
#pragma unroll
                for (int nt = 0; nt < 4; ++nt) {
                    float v = acc[m][nt][reg] + bv[nt];
                    acc[m][nt][reg] = v;
                    s += v; ss += v * v;
                }
#pragma unroll
                for (int msk = 1; msk < 16; msk <<= 1) {
                    s  += __shfl_xor(s,  msk, 64);
                    ss += __shfl_xor(ss, msk, 64);
                }
                if (lr == 0) {
                    atomicAdd(&sums [m * 16 + lg * 4 + reg], s);
                    atomicAdd(&ssums[m * 16 + lg * 4 + reg], ss);
                }
            }
        __syncthreads();
#pragma unroll
        for (int m = 0; m < 2; ++m)
#pragma unroll
            for (int reg = 0; reg < 4; ++reg) {
                int rl = m * 16 + lg * 4 + reg;
                float mean = sums[rl] * (1.f / 512.f);
                float var  = ssums[rl] * (1.f / 512.f) - mean * mean;
                float inv  = rsqrtf(var + LN_EPS);
#pragma unroll
                for (int nt = 0; nt < 4; ++nt) {
                    float v = fmaxf((acc[m][nt][reg] - mean) * inv * gv[nt] + be[nt], 0.f);
                    outb[(size_t)(rb + rl) * ldo + w * 64 + nt * 16 + lr] = f2bf(v);
                }
            }
    }
}

// ---------------------------------------------------------------------------
// NIN[:,0:64] = [X(32) | onehot(4) | zeros(28)]  (bf16, ld 576)
__global__ void concat64(const float* __restrict__ X, const int* __restrict__ act,
                         unsigned short* __restrict__ NIN)
{
    int idx = blockIdx.x * 256 + threadIdx.x;
    if (idx >= NNODES * 64) return;
    int r = idx >> 6, c = idx & 63;
    float v = 0.f;
    if (c < DIN) v = X[(size_t)r * DIN + c];
    else if (c < DIN + 4) v = (act[r / KOBJ] == (c - DIN)) ? 1.f : 0.f;
    NIN[(size_t)r * 576 + c] = f2bf(v);
}

// ---------------------------------------------------------------------------
// out[10240,32] = H2(bf16) @ nw3 + nb3 (f32 out)
__global__ __launch_bounds__(256) void out_v4(
    const unsigned short* __restrict__ H2, const float* __restrict__ W3,
    const float* __restrict__ b3, float* __restrict__ out)
{
    int t = threadIdx.x;
    int r = blockIdx.x * 8 + (t >> 5);
    int c = t & 31;
    const unsigned short* h = H2 + (size_t)r * HID;
    float acc = 0.f;
#pragma unroll 8
    for (int k8 = 0; k8 < 64; ++k8) {
        u16x8 hv = *(const u16x8*)(h + k8 * 8);
#pragma unroll
        for (int q = 0; q < 8; ++q)
            acc = fmaf(bf2f(hv[q]), W3[(k8 * 8 + q) * DIN + c], acc);
    }
    out[(size_t)r * DIN + c] = acc + b3[c];
}

// ---------------------------------------------------------------------------
extern "C" void kernel_launch(void* const* d_in, const int* in_sizes, int n_in,
                              void* d_out, int out_size, void* d_ws, size_t ws_size,
                              hipStream_t stream)
{
    const float* states = (const float*)d_in[0];
    const int*   action = (const int*)d_in[1];
    const float* ew1 = (const float*)d_in[2];
    const float* eb1 = (const float*)d_in[3];
    const float* ew2 = (const float*)d_in[4];
    const float* eb2 = (const float*)d_in[5];
    const float* eg  = (const float*)d_in[6];
    const float* ebt = (const float*)d_in[7];
    const float* ew3 = (const float*)d_in[8];
    const float* eb3 = (const float*)d_in[9];
    const float* nw1 = (const float*)d_in[10];
    const float* nb1 = (const float*)d_in[11];
    const float* nw2 = (const float*)d_in[12];
    const float* nb2 = (const float*)d_in[13];
    const float* ng  = (const float*)d_in[14];
    const float* nbt = (const float*)d_in[15];
    const float* nw3 = (const float*)d_in[16];
    const float* nb3 = (const float*)d_in[17];

    char* wsb = (char*)d_ws;
    // [0, 20.97M): PQ   [20.97M, 44.56M): h1 chunk (later aliased by NIN/Hh/H2)
    // [44.56M, 68.16M): H2e chunk        [68.16M, 78.64M): S    [78.64M+): packs
    unsigned short* PQ   = (unsigned short*)(wsb);               // 10240x1024 bf16
    unsigned short* h1   = (unsigned short*)(wsb + 20971520);    // 23040x512 bf16 (chunk)
    unsigned short* H2e  = (unsigned short*)(wsb + 44564480);    // 23040x512 bf16 (chunk)
    unsigned short* S    = (unsigned short*)(wsb + 68157440);    // 10240x512 bf16
    unsigned short* ew1p = (unsigned short*)(wsb + 78643200);    // 32x1024
    unsigned short* ew2p = (unsigned short*)(wsb + 78708736);    // 512x512
    unsigned short* ew3p = (unsigned short*)(wsb + 79233024);
    unsigned short* nw2p = (unsigned short*)(wsb + 79757312);
    unsigned short* nw1p = (unsigned short*)(wsb + 80281600);    // 576x512
    // aliases into dead h1/H2e region (used only after all chunks complete)
    unsigned short* NIN  = (unsigned short*)(wsb + 20971520);    // 10240x576
    unsigned short* Hh   = (unsigned short*)(wsb + 32768000);    // 10240x512
    unsigned short* H2   = (unsigned short*)(wsb + 43253760);    // 10240x512
    float* out = (float*)d_out;

    hipLaunchKernelGGL(pack_ew1, dim3(128), dim3(256), 0, stream, ew1, ew1p);
    hipLaunchKernelGGL(pack_w, dim3(1024), dim3(256), 0, stream, ew2, ew2p, 512 * 512);
    hipLaunchKernelGGL(pack_w, dim3(1024), dim3(256), 0, stream, ew3, ew3p, 512 * 512);
    hipLaunchKernelGGL(pack_w, dim3(1024), dim3(256), 0, stream, nw2, nw2p, 512 * 512);
    hipLaunchKernelGGL(pack_nw1, dim3(1152), dim3(256), 0, stream, nw1, nw1p);

    hipLaunchKernelGGL(pq_mfma, dim3(320, 2), dim3(256), 0, stream, states, ew1p, PQ);

    for (int c = 0; c < 4; ++c) {
        hipLaunchKernelGGL(h1_build, dim3(ROWS_C * 64 / 256), dim3(256), 0, stream,
                           PQ, eb1, h1, c * NG_C);
        hipLaunchKernelGGL(edge_gemm, dim3(ROWS_C / 64), dim3(512), 0, stream,
                           h1, ew2p, eb2, eg, ebt, H2e);
        hipLaunchKernelGGL(segsum, dim3(NODES_C * 64 / 256), dim3(256), 0, stream,
                           H2e, S, c * NODES_C);
    }

    hipLaunchKernelGGL((node_v4<0, 8, 512>), dim3(320), dim3(512), 0, stream,
                       S, ew3p, eb3, nullptr, nullptr, NIN, 576, 64);
    hipLaunchKernelGGL(concat64, dim3(2560), dim3(256), 0, stream, states, action, NIN);
    hipLaunchKernelGGL((node_v4<1, 9, 576>), dim3(320), dim3(512), 0, stream,
                       NIN, nw1p, nb1, nullptr, nullptr, Hh, 512, 0);
    hipLaunchKernelGGL((node_v4<2, 8, 512>), dim3(320), dim3(512), 0, stream,
                       Hh, nw2p, nb2, ng, nbt, H2, 512, 0);
    hipLaunchKernelGGL(out_v4, dim3(NNODES / 8), dim3(256), 0, stream,
                       H2, nw3, nb3, out);
}

// Round 6
// 232.009 us; speedup vs baseline: 7.1370x; 1.1215x over previous
//
#include <hip/hip_runtime.h>

// TransitionGNN forward, v6: weight-folded + fused edge path.
// B=1024 graphs, K=10 objects, D=32, H=512. Nodes N=10240, 90 edges/graph.
//
//  packs  : ew1->ew1p[32,1024]; ew2,nw2->frag-packed; nw1->nw1p (576 rows, remapped)
//  fold_w : Wfp = pack(ew3 @ nw1[36:548])          (512x512x512 MFMA, tiny)
//  bias_f : nbf = nb1 + 9*(eb3 @ nw1[36:548])
//  pq     : PQ[10240][1024] = X@[ew1_P|ew1_Q], +eb1 folded into P half
//  xa     : R[10240][512] f32 = [X|onehot]@nw1[0:64] + nbf     (K=64 MFMA)
//  edge   : H2e[92160][512] = relu(LN(relu(P[i]+Q[j])@ew2 + eb2)*eg+ebt)
//           A built in-register from PQ (1-step prefetch), B via global_load_lds dbuf
//  segsum : S[n] = sum_9 H2e rows  (bf16)
//  node_hh: Hh = relu(S@Wfp + R)
//  node_ln: H2 = relu(LN(Hh@nw2 + nb2)*ng+nbt)  (bf16)
//  out    : out = H2 @ nw3 + nb3  (f32)

#define HID 512
#define DIN 32
#define KOBJ 10
#define NGRAPH 1024
#define NNODES (NGRAPH*KOBJ)
#define NEDGE (NGRAPH*90)
#define LN_EPS 1e-5f

typedef __bf16 bf16x8 __attribute__((ext_vector_type(8)));
typedef unsigned short u16x8 __attribute__((ext_vector_type(8)));
typedef float f32x4 __attribute__((ext_vector_type(4)));

__device__ __forceinline__ unsigned short f2bf(float f) {
    unsigned u = __builtin_bit_cast(unsigned, f);
    u += 0x7fffu + ((u >> 16) & 1u);          // RNE
    return (unsigned short)(u >> 16);
}
__device__ __forceinline__ float bf2f(unsigned short h) {
    unsigned u = ((unsigned)h) << 16;
    return __builtin_bit_cast(float, u);
}
__device__ __forceinline__ void gl_lds16(const void* g, void* l) {
    __builtin_amdgcn_global_load_lds(
        (__attribute__((address_space(1))) void*)g,
        (__attribute__((address_space(3))) void*)l, 16, 0, 0);
}

// ---------------------------------------------------------------------------
// pack ew2/nw2: dst[(kb*512+c)*8+j] = bf16(src[(kb*8+j)*512+c])
__global__ void pack_w(const float* __restrict__ src, unsigned short* __restrict__ dst, int n)
{
    int idx = blockIdx.x * 256 + threadIdx.x;
    if (idx >= n) return;
    int j = idx & 7, c = (idx >> 3) & 511, kb = idx >> 12;
    dst[idx] = f2bf(src[(size_t)(kb * 8 + j) * 512 + c]);
}

// nw1 packed with row remap: k<36 -> k ; 36..63 -> zero ; k>=64 -> k-28
__global__ void pack_nw1(const float* __restrict__ src, unsigned short* __restrict__ dst)
{
    int idx = blockIdx.x * 256 + threadIdx.x;
    if (idx >= 576 * 512) return;
    int j = idx & 7, c = (idx >> 3) & 511, kb = idx >> 12;
    int k = kb * 8 + j;
    int sk = (k < 36) ? k : (k < 64 ? -1 : k - 28);
    dst[idx] = f2bf(sk < 0 ? 0.f : src[(size_t)sk * 512 + c]);
}

// ew1p [32,1024]: cols 0..511 from ew1[0:32], cols 512..1023 from ew1[32:64]
__global__ void pack_ew1(const float* __restrict__ src, unsigned short* __restrict__ dst)
{
    int idx = blockIdx.x * 256 + threadIdx.x;
    if (idx >= 32 * 1024) return;
    int j = idx & 7, c = (idx >> 3) & 1023, kb = idx >> 13;
    int k = kb * 8 + j;
    float v = (c < 512) ? src[(size_t)k * 512 + c] : src[(size_t)(32 + k) * 512 + (c - 512)];
    dst[idx] = f2bf(v);
}

// ---------------------------------------------------------------------------
// Wfp = pack( ew3 @ nw1[36:548] ). 32 blocks x 512 thr; 16 output rows/block.
__global__ __launch_bounds__(512) void fold_w(
    const float* __restrict__ ew3, const unsigned short* __restrict__ nw1p,
    unsigned short* __restrict__ Wfp)
{
    const int t = threadIdx.x, w = t >> 6, lane = t & 63;
    const int lr = lane & 15, lg = lane >> 4;
    const int rb = blockIdx.x * 16;
    f32x4 acc[4] = {};
    for (int kc = 0; kc < 16; ++kc) {
        const float* s = ew3 + (size_t)(rb + lr) * 512 + kc * 32 + lg * 8;
        float4 x0 = *(const float4*)s, x1 = *(const float4*)(s + 4);
        u16x8 u;
        u[0] = f2bf(x0.x); u[1] = f2bf(x0.y); u[2] = f2bf(x0.z); u[3] = f2bf(x0.w);
        u[4] = f2bf(x1.x); u[5] = f2bf(x1.y); u[6] = f2bf(x1.z); u[7] = f2bf(x1.w);
        bf16x8 a = __builtin_bit_cast(bf16x8, u);
        const size_t kb = (size_t)(8 + kc * 4 + lg) * 512;
#pragma unroll
        for (int nt = 0; nt < 4; ++nt) {
            int c = w * 64 + nt * 16 + lr;
            bf16x8 b = __builtin_bit_cast(bf16x8, *(const u16x8*)(nw1p + (kb + c) * 8));
            acc[nt] = __builtin_amdgcn_mfma_f32_16x16x32_bf16(a, b, acc[nt], 0, 0, 0);
        }
    }
#pragma unroll
    for (int reg = 0; reg < 4; ++reg)
#pragma unroll
        for (int nt = 0; nt < 4; ++nt) {
            int k = rb + lg * 4 + reg;
            int c = w * 64 + nt * 16 + lr;
            Wfp[((size_t)(k >> 3) * 512 + c) * 8 + (k & 7)] = f2bf(acc[nt][reg]);
        }
}

// nbf[c] = nb1[c] + 9 * sum_m eb3[m]*nw1[36+m][c]
__global__ __launch_bounds__(512) void bias_fold(
    const float* __restrict__ nb1, const float* __restrict__ eb3,
    const float* __restrict__ nw1, float* __restrict__ nbf)
{
    int c = threadIdx.x;
    float s = 0.f;
    for (int m = 0; m < 512; ++m)
        s = fmaf(eb3[m], nw1[(size_t)(36 + m) * 512 + c], s);
    nbf[c] = nb1[c] + 9.f * s;
}

// ---------------------------------------------------------------------------
// PQ = X @ ew1p (+eb1 on P half). 320x2 blocks, 256 thr.
__global__ __launch_bounds__(256) void pq_mfma(
    const float* __restrict__ X, const unsigned short* __restrict__ ew1p,
    const float* __restrict__ eb1, unsigned short* __restrict__ PQ)
{
    const int t = threadIdx.x, w = t >> 6, lane = t & 63;
    const int lr = lane & 15, lg = lane >> 4;
    const int rb = blockIdx.x * 32;
    const int half = blockIdx.y;

    bf16x8 a[2];
#pragma unroll
    for (int m = 0; m < 2; ++m) {
        const float* s = X + (size_t)(rb + m * 16 + lr) * 32 + lg * 8;
        float4 x0 = *(const float4*)s, x1 = *(const float4*)(s + 4);
        u16x8 u;
        u[0] = f2bf(x0.x); u[1] = f2bf(x0.y); u[2] = f2bf(x0.z); u[3] = f2bf(x0.w);
        u[4] = f2bf(x1.x); u[5] = f2bf(x1.y); u[6] = f2bf(x1.z); u[7] = f2bf(x1.w);
        a[m] = __builtin_bit_cast(bf16x8, u);
    }
    f32x4 acc[2][8] = {};
#pragma unroll
    for (int nt = 0; nt < 8; ++nt) {
        int col = half * 512 + w * 128 + nt * 16 + lr;
        bf16x8 b = __builtin_bit_cast(bf16x8, *(const u16x8*)(ew1p + ((size_t)lg * 1024 + col) * 8));
        acc[0][nt] = __builtin_amdgcn_mfma_f32_16x16x32_bf16(a[0], b, acc[0][nt], 0, 0, 0);
        acc[1][nt] = __builtin_amdgcn_mfma_f32_16x16x32_bf16(a[1], b, acc[1][nt], 0, 0, 0);
    }
#pragma unroll
    for (int nt = 0; nt < 8; ++nt) {
        int col = w * 128 + nt * 16 + lr;
        float eb = (half == 0) ? eb1[col] : 0.f;
#pragma unroll
        for (int m = 0; m < 2; ++m)
#pragma unroll
            for (int reg = 0; reg < 4; ++reg)
                PQ[(size_t)(rb + m * 16 + lg * 4 + reg) * 1024 + half * 512 + col]
                    = f2bf(acc[m][nt][reg] + eb);
    }
}

// ---------------------------------------------------------------------------
// R = [X|onehot]@nw1[0:64] + nbf   (f32 out). 320 blocks x 256 thr.
__global__ __launch_bounds__(256) void xa_mfma(
    const float* __restrict__ X, const int* __restrict__ act,
    const unsigned short* __restrict__ nw1p, const float* __restrict__ nbf,
    float* __restrict__ R)
{
    const int t = threadIdx.x, w = t >> 6, lane = t & 63;
    const int lr = lane & 15, lg = lane >> 4;
    const int rb = blockIdx.x * 32;

    bf16x8 a0[2], a1[2];
#pragma unroll
    for (int m = 0; m < 2; ++m) {
        int row = rb + m * 16 + lr;
        const float* s = X + (size_t)row * 32 + lg * 8;
        float4 x0 = *(const float4*)s, x1 = *(const float4*)(s + 4);
        u16x8 u;
        u[0] = f2bf(x0.x); u[1] = f2bf(x0.y); u[2] = f2bf(x0.z); u[3] = f2bf(x0.w);
        u[4] = f2bf(x1.x); u[5] = f2bf(x1.y); u[6] = f2bf(x1.z); u[7] = f2bf(x1.w);
        a0[m] = __builtin_bit_cast(bf16x8, u);
        u16x8 v = (u16x8)(unsigned short)0;
        if (lg == 0) {
            int ac = act[row / KOBJ];           // k = 32+q -> onehot
            v[ac & 3] = (unsigned short)0x3f80; // bf16(1.0)
        }
        a1[m] = __builtin_bit_cast(bf16x8, v);
    }
    f32x4 acc[2][8] = {};
#pragma unroll
    for (int nt = 0; nt < 8; ++nt) {
        int col = w * 128 + nt * 16 + lr;
        bf16x8 b0 = __builtin_bit_cast(bf16x8, *(const u16x8*)(nw1p + ((size_t)lg * 512 + col) * 8));
        bf16x8 b1 = __builtin_bit_cast(bf16x8, *(const u16x8*)(nw1p + ((size_t)(4 + lg) * 512 + col) * 8));
#pragma unroll
        for (int m = 0; m < 2; ++m) {
            acc[m][nt] = __builtin_amdgcn_mfma_f32_16x16x32_bf16(a0[m], b0, acc[m][nt], 0, 0, 0);
            acc[m][nt] = __builtin_amdgcn_mfma_f32_16x16x32_bf16(a1[m], b1, acc[m][nt], 0, 0, 0);
        }
    }
#pragma unroll
    for (int nt = 0; nt < 8; ++nt) {
        int col = w * 128 + nt * 16 + lr;
        float bb = nbf[col];
#pragma unroll
        for (int m = 0; m < 2; ++m)
#pragma unroll
            for (int reg = 0; reg < 4; ++reg)
                R[(size_t)(rb + m * 16 + lg * 4 + reg) * 512 + col] = acc[m][nt][reg] + bb;
    }
}

// ---------------------------------------------------------------------------
// Edge GEMM v6: H2e[64 x 512] tile = relu(LN(relu(P[i]+Q[j]) @ ew2 + eb2)*eg+ebt).
// 512 thr = 8 waves (2x4), BK=32. A built in-register from PQ (1-step prefetch),
// ds_write staged; B via global_load_lds, both double-buffered.
__global__ __launch_bounds__(512, 4) void edge_v6(
    const unsigned short* __restrict__ PQ, const unsigned short* __restrict__ ew2p,
    const float* __restrict__ eb2, const float* __restrict__ eg,
    const float* __restrict__ ebt, unsigned short* __restrict__ H2e)
{
    __shared__ __align__(16) unsigned short Bsh[2][16384];  // 2 x 32KB
    __shared__ __align__(16) unsigned short Ash[2][2048];   // 2 x 4KB [row64][kg4][8]
    __shared__ float sums[64], ssums[64];

    const int t = threadIdx.x, w = t >> 6, lane = t & 63;
    const int lr = lane & 15, lg = lane >> 4;
    const int wr = w >> 2, wc = w & 3;
    const int rb = blockIdx.x * 64;

    if (t < 64) { sums[t] = 0.f; ssums[t] = 0.f; }

    // A-build: threads t<256, one 16B granule each. row=t>>2 (0..63), kg=t&3.
    const bool ab = (t < 256);
    const int arow = t >> 2, akg = t & 3;
    const int e = rb + arow;
    const int g = e / 90, le = e - g * 90;
    const int i = le / 9, jj = le - i * 9;
    const int j = jj + (jj >= i);
    const unsigned short* pqP = PQ + ((size_t)(g * KOBJ + i)) * 1024 + akg * 8;
    const unsigned short* pqQ = PQ + ((size_t)(g * KOBJ + j)) * 1024 + 512 + akg * 8;

    u16x8 rp = (u16x8)(unsigned short)0, rq = (u16x8)(unsigned short)0;
    auto loadPQ = [&](int kc) {
        if (ab) {
            rp = *(const u16x8*)(pqP + kc * 32);
            rq = *(const u16x8*)(pqQ + kc * 32);
        }
    };
    auto buildA = [&](int buf) {
        if (ab) {
            u16x8 o;
#pragma unroll
            for (int q = 0; q < 8; ++q)
                o[q] = f2bf(fmaxf(bf2f(rp[q]) + bf2f(rq[q]), 0.f));
            *(u16x8*)(&Ash[buf][arow * 32 + akg * 8]) = o;
        }
    };
    auto fillB = [&](int kc, int buf) {
        char* Bb = (char*)&Bsh[buf][0];
#pragma unroll
        for (int RR = 0; RR < 4; ++RR)
            gl_lds16(ew2p + (size_t)kc * 16384 + RR * 4096 + t * 8, Bb + RR * 8192 + w * 1024);
    };

    f32x4 acc[2][8] = {};
    loadPQ(0); buildA(0); loadPQ(1); fillB(0, 0);
    __syncthreads();
    int cur = 0;
    for (int kc = 0; kc < 16; ++kc) {
        if (kc < 15) {
            fillB(kc + 1, cur ^ 1);
            buildA(cur ^ 1);              // consumes regs prefetched for kc+1
            if (kc < 14) loadPQ(kc + 2);
        }
        const unsigned short* Ab = &Ash[cur][0];
        const unsigned short* Bb = &Bsh[cur][0];
        bf16x8 a0 = *(const bf16x8*)(Ab + (wr * 32 + lr) * 32 + lg * 8);
        bf16x8 a1 = *(const bf16x8*)(Ab + (wr * 32 + 16 + lr) * 32 + lg * 8);
#pragma unroll
        for (int nt = 0; nt < 8; ++nt) {
            bf16x8 b = *(const bf16x8*)(Bb + ((size_t)lg * 512 + wc * 128 + nt * 16 + lr) * 8);
            acc[0][nt] = __builtin_amdgcn_mfma_f32_16x16x32_bf16(a0, b, acc[0][nt], 0, 0, 0);
            acc[1][nt] = __builtin_amdgcn_mfma_f32_16x16x32_bf16(a1, b, acc[1][nt], 0, 0, 0);
        }
        __syncthreads();
        cur ^= 1;
    }

    // epilogue: +eb2, LN (cross-wave via LDS), *eg+ebt, relu -> H2e
    float b2[8], gv[8], bb[8];
#pragma unroll
    for (int nt = 0; nt < 8; ++nt) {
        int c = wc * 128 + nt * 16 + lr;
        b2[nt] = eb2[c]; gv[nt] = eg[c]; bb[nt] = ebt[c];
    }
#pragma unroll
    for (int m = 0; m < 2; ++m)
#pragma unroll
        for (int reg = 0; reg < 4; ++reg) {
            float s = 0.f, ss = 0.f;
#pragma unroll
            for (int nt = 0; nt < 8; ++nt) {
                float v = acc[m][nt][reg] + b2[nt];
                acc[m][nt][reg] = v;
                s += v; ss += v * v;
            }
#pragma unroll
            for (int msk = 1; msk < 16; msk <<= 1) {
                s  += __shfl_xor(s,  msk, 64);
                ss += __shfl_xor(ss, msk, 64);
            }
            if (lr == 0) {
                int rl = wr * 32 + m * 16 + lg * 4 + reg;
                atomicAdd(&sums[rl], s);
                atomicAdd(&ssums[rl], ss);
            }
        }
    __syncthreads();
#pragma unroll
    for (int m = 0; m < 2; ++m)
#pragma unroll
        for (int reg = 0; reg < 4; ++reg) {
            int rl = wr * 32 + m * 16 + lg * 4 + reg;
            float mean = sums[rl] * (1.f / 512.f);
            float var  = ssums[rl] * (1.f / 512.f) - mean * mean;
            float inv  = rsqrtf(var + LN_EPS);
#pragma unroll
            for (int nt = 0; nt < 8; ++nt) {
                float h = fmaxf((acc[m][nt][reg] - mean) * inv * gv[nt] + bb[nt], 0.f);
                H2e[(size_t)(rb + rl) * 512 + wc * 128 + nt * 16 + lr] = f2bf(h);
            }
        }
}

// ---------------------------------------------------------------------------
// S[n] = sum_{k=0..8} H2e[n*9+k]   (bf16 in/out, f32 accumulate)
__global__ __launch_bounds__(256) void segsum(
    const unsigned short* __restrict__ H2e, unsigned short* __restrict__ S)
{
    int idx = blockIdx.x * 256 + threadIdx.x;       // < NNODES * 64
    int n = idx >> 6, c8 = idx & 63;
    float acc[8] = {};
#pragma unroll
    for (int k = 0; k < 9; ++k) {
        u16x8 v = *(const u16x8*)(H2e + ((size_t)(n * 9 + k)) * 512 + c8 * 8);
#pragma unroll
        for (int q = 0; q < 8; ++q) acc[q] += bf2f(v[q]);
    }
    u16x8 o;
#pragma unroll
    for (int q = 0; q < 8; ++q) o[q] = f2bf(acc[q]);
    *(u16x8*)(S + ((size_t)n) * 512 + c8 * 8) = o;
}

// ---------------------------------------------------------------------------
// Hh = relu(S @ Wfp + R).  M=32/block, BK=64, gl_lds staged. 320 blocks.
__global__ __launch_bounds__(512, 4) void node_hh(
    const unsigned short* __restrict__ S, const unsigned short* __restrict__ Wfp,
    const float* __restrict__ R, unsigned short* __restrict__ Hh)
{
    __shared__ __align__(16) unsigned short Bt[32768];
    __shared__ __align__(16) unsigned short At[2048];
    const int t = threadIdx.x, w = t >> 6, lane = t & 63;
    const int lr = lane & 15, lg = lane >> 4;
    const int rb = blockIdx.x * 32;

    f32x4 acc[2][4] = {};
    for (int kc = 0; kc < 8; ++kc) {
        __syncthreads();
#pragma unroll
        for (int RR = 0; RR < 8; ++RR)
            gl_lds16(Wfp + ((size_t)kc * 4096 + RR * 512 + t) * 8,
                     (char*)Bt + RR * 8192 + w * 1024);
        if (w < 4) {
            int row = t >> 3, cp = t & 7;
            int scol = cp ^ (row & 7);
            gl_lds16(S + (size_t)(rb + row) * 512 + kc * 64 + scol * 8,
                     (char*)At + (t & ~63) * 16);
        }
        __syncthreads();
#pragma unroll
        for (int ks = 0; ks < 2; ++ks) {
            int kidx = ks * 4 + lg;
            bf16x8 a0 = *(const bf16x8*)(At + ( 0 + lr) * 64 + (kidx ^ (lr & 7)) * 8);
            bf16x8 a1 = *(const bf16x8*)(At + (16 + lr) * 64 + (kidx ^ (lr & 7)) * 8);
#pragma unroll
            for (int nt = 0; nt < 4; ++nt) {
                bf16x8 b = *(const bf16x8*)(Bt + ((size_t)kidx * 512 + w * 64 + nt * 16 + lr) * 8);
                acc[0][nt] = __builtin_amdgcn_mfma_f32_16x16x32_bf16(a0, b, acc[0][nt], 0, 0, 0);
                acc[1][nt] = __builtin_amdgcn_mfma_f32_16x16x32_bf16(a1, b, acc[1][nt], 0, 0, 0);
            }
        }
    }
#pragma unroll
    for (int m = 0; m < 2; ++m)
#pragma unroll
        for (int reg = 0; reg < 4; ++reg) {
            int row = rb + m * 16 + lg * 4 + reg;
#pragma unroll
            for (int nt = 0; nt < 4; ++nt) {
                int c = w * 64 + nt * 16 + lr;
                float v = acc[m][nt][reg] + R[(size_t)row * 512 + c];
                Hh[(size_t)row * 512 + c] = f2bf(fmaxf(v, 0.f));
            }
        }
}

// ---------------------------------------------------------------------------
// H2 = relu(LN(Hh@nw2 + nb2)*ng+nbt)  (bf16 out). Same staging as node_hh.
__global__ __launch_bounds__(512, 4) void node_ln(
    const unsigned short* __restrict__ A, const unsigned short* __restrict__ Wp,
    const float* __restrict__ bias, const float* __restrict__ gamma,
    const float* __restrict__ beta, unsigned short* __restrict__ outb)
{
    __shared__ __align__(16) unsigned short Bt[32768];
    __shared__ __align__(16) unsigned short At[2048];
    __shared__ float sums[32], ssums[32];
    const int t = threadIdx.x, w = t >> 6, lane = t & 63;
    const int lr = lane & 15, lg = lane >> 4;
    const int rb = blockIdx.x * 32;
    if (t < 32) { sums[t] = 0.f; ssums[t] = 0.f; }

    f32x4 acc[2][4] = {};
    for (int kc = 0; kc < 8; ++kc) {
        __syncthreads();
#pragma unroll
        for (int RR = 0; RR < 8; ++RR)
            gl_lds16(Wp + ((size_t)kc * 4096 + RR * 512 + t) * 8,
                     (char*)Bt + RR * 8192 + w * 1024);
        if (w < 4) {
            int row = t >> 3, cp = t & 7;
            int scol = cp ^ (row & 7);
            gl_lds16(A + (size_t)(rb + row) * 512 + kc * 64 + scol * 8,
                     (char*)At + (t & ~63) * 16);
        }
        __syncthreads();
#pragma unroll
        for (int ks = 0; ks < 2; ++ks) {
            int kidx = ks * 4 + lg;
            bf16x8 a0 = *(const bf16x8*)(At + ( 0 + lr) * 64 + (kidx ^ (lr & 7)) * 8);
            bf16x8 a1 = *(const bf16x8*)(At + (16 + lr) * 64 + (kidx ^ (lr & 7)) * 8);
#pragma unroll
            for (int nt = 0; nt < 4; ++nt) {
                bf16x8 b = *(const bf16x8*)(Bt + ((size_t)kidx * 512 + w * 64 + nt * 16 + lr) * 8);
                acc[0][nt] = __builtin_amdgcn_mfma_f32_16x16x32_bf16(a0, b, acc[0][nt], 0, 0, 0);
                acc[1][nt] = __builtin_amdgcn_mfma_f32_16x16x32_bf16(a1, b, acc[1][nt], 0, 0, 0);
            }
        }
    }

    float bv[4], gv[4], be[4];
#pragma unroll
    for (int nt = 0; nt < 4; ++nt) {
        int c = w * 64 + nt * 16 + lr;
        bv[nt] = bias[c]; gv[nt] = gamma[c]; be[nt] = beta[c];
    }
#pragma unroll
    for (int m = 0; m < 2; ++m)
#pragma unroll
        for (int reg = 0; reg < 4; ++reg) {
            float s = 0.f, ss = 0.f;
#pragma unroll
            for (int nt = 0; nt < 4; ++nt) {
                float v = acc[m][nt][reg] + bv[nt];
                acc[m][nt][reg] = v;
                s += v; ss += v * v;
            }
#pragma unroll
            for (int msk = 1; msk < 16; msk <<= 1) {
                s  += __shfl_xor(s,  msk, 64);
                ss += __shfl_xor(ss, msk, 64);
            }
            if (lr == 0) {
                atomicAdd(&sums [m * 16 + lg * 4 + reg], s);
                atomicAdd(&ssums[m * 16 + lg * 4 + reg], ss);
            }
        }
    __syncthreads();
#pragma unroll
    for (int m = 0; m < 2; ++m)
#pragma unroll
        for (int reg = 0; reg < 4; ++reg) {
            int rl = m * 16 + lg * 4 + reg;
            float mean = sums[rl] * (1.f / 512.f);
            float var  = ssums[rl] * (1.f / 512.f) - mean * mean;
            float inv  = rsqrtf(var + LN_EPS);
#pragma unroll
            for (int nt = 0; nt < 4; ++nt) {
                float v = fmaxf((acc[m][nt][reg] - mean) * inv * gv[nt] + be[nt], 0.f);
                outb[(size_t)(rb + rl) * 512 + w * 64 + nt * 16 + lr] = f2bf(v);
            }
        }
}

// ---------------------------------------------------------------------------
// out[10240,32] = H2(bf16) @ nw3 + nb3 (f32 out)
__global__ __launch_bounds__(256) void out_v4(
    const unsigned short* __restrict__ H2, const float* __restrict__ W3,
    const float* __restrict__ b3, float* __restrict__ out)
{
    int t = threadIdx.x;
    int r = blockIdx.x * 8 + (t >> 5);
    int c = t & 31;
    const unsigned short* h = H2 + (size_t)r * HID;
    float acc = 0.f;
#pragma unroll 8
    for (int k8 = 0; k8 < 64; ++k8) {
        u16x8 hv = *(const u16x8*)(h + k8 * 8);
#pragma unroll
        for (int q = 0; q < 8; ++q)
            acc = fmaf(bf2f(hv[q]), W3[(k8 * 8 + q) * DIN + c], acc);
    }
    out[(size_t)r * DIN + c] = acc + b3[c];
}

// ---------------------------------------------------------------------------
extern "C" void kernel_launch(void* const* d_in, const int* in_sizes, int n_in,
                              void* d_out, int out_size, void* d_ws, size_t ws_size,
                              hipStream_t stream)
{
    const float* states = (const float*)d_in[0];
    const int*   action = (const int*)d_in[1];
    const float* ew1 = (const float*)d_in[2];
    const float* eb1 = (const float*)d_in[3];
    const float* ew2 = (const float*)d_in[4];
    const float* eb2 = (const float*)d_in[5];
    const float* eg  = (const float*)d_in[6];
    const float* ebt = (const float*)d_in[7];
    const float* ew3 = (const float*)d_in[8];
    const float* eb3 = (const float*)d_in[9];
    const float* nw1 = (const float*)d_in[10];
    const float* nb1 = (const float*)d_in[11];
    const float* nw2 = (const float*)d_in[12];
    const float* nb2 = (const float*)d_in[13];
    const float* ng  = (const float*)d_in[14];
    const float* nbt = (const float*)d_in[15];
    const float* nw3 = (const float*)d_in[16];
    const float* nb3 = (const float*)d_in[17];

    char* wsb = (char*)d_ws;
    unsigned short* PQ   = (unsigned short*)(wsb);                // 10240x1024 bf16  (21.0M)
    unsigned short* H2e  = (unsigned short*)(wsb + 20971520);     // 92160x512 bf16   (94.4M)
    unsigned short* S    = (unsigned short*)(wsb + 115343360);    // 10240x512 bf16   (10.5M)
    float*          R    = (float*)         (wsb + 125829120);    // 10240x512 f32    (21.0M)
    unsigned short* Hh   = (unsigned short*)(wsb + 146800640);    // 10240x512 bf16
    unsigned short* H2   = (unsigned short*)(wsb + 157286400);    // 10240x512 bf16
    unsigned short* ew1p = (unsigned short*)(wsb + 167772160);    // 32x1024
    unsigned short* ew2p = (unsigned short*)(wsb + 167837696);    // 512x512 packed
    unsigned short* nw1p = (unsigned short*)(wsb + 168361984);    // 576x512 packed
    unsigned short* nw2p = (unsigned short*)(wsb + 168951808);    // 512x512 packed
    unsigned short* Wfp  = (unsigned short*)(wsb + 169476096);    // 512x512 packed
    float*          nbf  = (float*)         (wsb + 170000384);    // 512 f32
    float* out = (float*)d_out;

    hipLaunchKernelGGL(pack_ew1, dim3(128), dim3(256), 0, stream, ew1, ew1p);
    hipLaunchKernelGGL(pack_w, dim3(1024), dim3(256), 0, stream, ew2, ew2p, 512 * 512);
    hipLaunchKernelGGL(pack_nw1, dim3(1152), dim3(256), 0, stream, nw1, nw1p);
    hipLaunchKernelGGL(pack_w, dim3(1024), dim3(256), 0, stream, nw2, nw2p, 512 * 512);
    hipLaunchKernelGGL(fold_w, dim3(32), dim3(512), 0, stream, ew3, nw1p, Wfp);
    hipLaunchKernelGGL(bias_fold, dim3(1), dim3(512), 0, stream, nb1, eb3, nw1, nbf);

    hipLaunchKernelGGL(pq_mfma, dim3(320, 2), dim3(256), 0, stream, states, ew1p, eb1, PQ);
    hipLaunchKernelGGL(xa_mfma, dim3(320), dim3(256), 0, stream, states, action, nw1p, nbf, R);

    hipLaunchKernelGGL(edge_v6, dim3(NEDGE / 64), dim3(512), 0, stream,
                       PQ, ew2p, eb2, eg, ebt, H2e);
    hipLaunchKernelGGL(segsum, dim3(NNODES * 64 / 256), dim3(256), 0, stream, H2e, S);

    hipLaunchKernelGGL(node_hh, dim3(320), dim3(512), 0, stream, S, Wfp, R, Hh);
    hipLaunchKernelGGL(node_ln, dim3(320), dim3(512), 0, stream, Hh, nw2p, nb2, ng, nbt, H2);
    hipLaunchKernelGGL(out_v4, dim3(NNODES / 8), dim3(256), 0, stream, H2, nw3, nb3, out);
}

// Round 7
// 209.270 us; speedup vs baseline: 7.9125x; 1.1087x over previous
//
#include <hip/hip_runtime.h>

// TransitionGNN forward, v7: edge kernel with fused aggregation; 7 launches.
// B=1024 graphs, K=10 objects, D=32, H=512. Nodes N=10240, 90 edges/graph.
//
//  megapack : ew1p[32,1024], ew2p, nw1p(576 remap), nw2p   (one kernel)
//  fold_w2  : Wfp = pack(ew3 @ nw1[36:548]) ; nbf = nb1 + 9*eb3@nw1[36:548]
//  pq_xa    : PQ[10240][1024] = X@[ew1_P|ew1_Q] (+eb1 on P half)
//             R[10240][512] f32 = [X|onehot]@nw1[0:64] + nbf
//  edge_v7  : per half-graph (45 edges pad 48): A=relu(P[i]+Q[j]) in-reg build,
//             GEMM vs ew2 (B gl_lds dbuf), +eb2, LN, *eg+ebt, relu,
//             per-node sum via col-major LDS stage -> S bf16 (no H2e!)
//  node_hh  : Hh = relu(S@Wfp + R)
//  node_ln  : H2 = relu(LN(Hh@nw2 + nb2)*ng+nbt)  (bf16)
//  out_v4   : out = H2 @ nw3 + nb3  (f32)

#define HID 512
#define DIN 32
#define KOBJ 10
#define NGRAPH 1024
#define NNODES (NGRAPH*KOBJ)
#define LN_EPS 1e-5f

typedef __bf16 bf16x8 __attribute__((ext_vector_type(8)));
typedef unsigned short u16x8 __attribute__((ext_vector_type(8)));
typedef unsigned short u16x4 __attribute__((ext_vector_type(4)));
typedef float f32x4 __attribute__((ext_vector_type(4)));

__device__ __forceinline__ unsigned short f2bf(float f) {
    unsigned u = __builtin_bit_cast(unsigned, f);
    u += 0x7fffu + ((u >> 16) & 1u);          // RNE
    return (unsigned short)(u >> 16);
}
__device__ __forceinline__ float bf2f(unsigned short h) {
    unsigned u = ((unsigned)h) << 16;
    return __builtin_bit_cast(float, u);
}
__device__ __forceinline__ void gl_lds16(const void* g, void* l) {
    __builtin_amdgcn_global_load_lds(
        (__attribute__((address_space(1))) void*)g,
        (__attribute__((address_space(3))) void*)l, 16, 0, 0);
}

// ---------------------------------------------------------------------------
// megapack: ew1p | ew2p | nw1p | nw2p in one launch.
__global__ void megapack(const float* __restrict__ ew1, const float* __restrict__ ew2,
                         const float* __restrict__ nw1, const float* __restrict__ nw2,
                         unsigned short* __restrict__ ew1p, unsigned short* __restrict__ ew2p,
                         unsigned short* __restrict__ nw1p, unsigned short* __restrict__ nw2p)
{
    int idx = blockIdx.x * 256 + threadIdx.x;
    if (idx < 32768) {                                   // ew1p [32,1024]
        int j = idx & 7, c = (idx >> 3) & 1023, kb = idx >> 13;
        int k = kb * 8 + j;
        float v = (c < 512) ? ew1[(size_t)k * 512 + c]
                            : ew1[(size_t)(32 + k) * 512 + (c - 512)];
        ew1p[idx] = f2bf(v);
    } else if (idx < 32768 + 262144) {                   // ew2p
        int i = idx - 32768;
        int j = i & 7, c = (i >> 3) & 511, kb = i >> 12;
        ew2p[i] = f2bf(ew2[(size_t)(kb * 8 + j) * 512 + c]);
    } else if (idx < 294912 + 294912) {                  // nw1p (576 rows, remap)
        int i = idx - 294912;
        int j = i & 7, c = (i >> 3) & 511, kb = i >> 12;
        int k = kb * 8 + j;
        int sk = (k < 36) ? k : (k < 64 ? -1 : k - 28);
        nw1p[i] = f2bf(sk < 0 ? 0.f : nw1[(size_t)sk * 512 + c]);
    } else if (idx < 589824 + 262144) {                  // nw2p
        int i = idx - 589824;
        int j = i & 7, c = (i >> 3) & 511, kb = i >> 12;
        nw2p[i] = f2bf(nw2[(size_t)(kb * 8 + j) * 512 + c]);
    }
}

// ---------------------------------------------------------------------------
// fold_w2: blocks 0..31: Wfp = pack(ew3 @ nw1[36:548]); block 32: nbf fold.
__global__ __launch_bounds__(512) void fold_w2(
    const float* __restrict__ ew3, const unsigned short* __restrict__ nw1p,
    const float* __restrict__ nw1, const float* __restrict__ nb1,
    const float* __restrict__ eb3, unsigned short* __restrict__ Wfp,
    float* __restrict__ nbf)
{
    if (blockIdx.x == 32) {
        int c = threadIdx.x;
        if (c < 512) {
            float s = 0.f;
            for (int m = 0; m < 512; ++m)
                s = fmaf(eb3[m], nw1[(size_t)(36 + m) * 512 + c], s);
            nbf[c] = nb1[c] + 9.f * s;
        }
        return;
    }
    const int t = threadIdx.x, w = t >> 6, lane = t & 63;
    const int lr = lane & 15, lg = lane >> 4;
    const int rb = blockIdx.x * 16;
    f32x4 acc[4] = {};
    for (int kc = 0; kc < 16; ++kc) {
        const float* s = ew3 + (size_t)(rb + lr) * 512 + kc * 32 + lg * 8;
        float4 x0 = *(const float4*)s, x1 = *(const float4*)(s + 4);
        u16x8 u;
        u[0] = f2bf(x0.x); u[1] = f2bf(x0.y); u[2] = f2bf(x0.z); u[3] = f2bf(x0.w);
        u[4] = f2bf(x1.x); u[5] = f2bf(x1.y); u[6] = f2bf(x1.z); u[7] = f2bf(x1.w);
        bf16x8 a = __builtin_bit_cast(bf16x8, u);
        const size_t kb = (size_t)(8 + kc * 4 + lg) * 512;
#pragma unroll
        for (int nt = 0; nt < 4; ++nt) {
            int c = w * 64 + nt * 16 + lr;
            bf16x8 b = __builtin_bit_cast(bf16x8, *(const u16x8*)(nw1p + (kb + c) * 8));
            acc[nt] = __builtin_amdgcn_mfma_f32_16x16x32_bf16(a, b, acc[nt], 0, 0, 0);
        }
    }
#pragma unroll
    for (int reg = 0; reg < 4; ++reg)
#pragma unroll
        for (int nt = 0; nt < 4; ++nt) {
            int k = rb + lg * 4 + reg;
            int c = w * 64 + nt * 16 + lr;
            Wfp[((size_t)(k >> 3) * 512 + c) * 8 + (k & 7)] = f2bf(acc[nt][reg]);
        }
}

// ---------------------------------------------------------------------------
// pq_xa: y<2 -> PQ halves (+eb1 on P); y==2 -> R = [X|onehot]@nw1[0:64]+nbf.
__global__ __launch_bounds__(256) void pq_xa(
    const float* __restrict__ X, const int* __restrict__ act,
    const unsigned short* __restrict__ ew1p, const unsigned short* __restrict__ nw1p,
    const float* __restrict__ eb1, const float* __restrict__ nbf,
    unsigned short* __restrict__ PQ, float* __restrict__ R)
{
    const int t = threadIdx.x, w = t >> 6, lane = t & 63;
    const int lr = lane & 15, lg = lane >> 4;
    const int rb = blockIdx.x * 32;
    const int mode = blockIdx.y;

    bf16x8 a[2];
#pragma unroll
    for (int m = 0; m < 2; ++m) {
        const float* s = X + (size_t)(rb + m * 16 + lr) * 32 + lg * 8;
        float4 x0 = *(const float4*)s, x1 = *(const float4*)(s + 4);
        u16x8 u;
        u[0] = f2bf(x0.x); u[1] = f2bf(x0.y); u[2] = f2bf(x0.z); u[3] = f2bf(x0.w);
        u[4] = f2bf(x1.x); u[5] = f2bf(x1.y); u[6] = f2bf(x1.z); u[7] = f2bf(x1.w);
        a[m] = __builtin_bit_cast(bf16x8, u);
    }

    if (mode < 2) {
        const int half = mode;
        f32x4 acc[2][8] = {};
#pragma unroll
        for (int nt = 0; nt < 8; ++nt) {
            int col = half * 512 + w * 128 + nt * 16 + lr;
            bf16x8 b = __builtin_bit_cast(bf16x8, *(const u16x8*)(ew1p + ((size_t)lg * 1024 + col) * 8));
            acc[0][nt] = __builtin_amdgcn_mfma_f32_16x16x32_bf16(a[0], b, acc[0][nt], 0, 0, 0);
            acc[1][nt] = __builtin_amdgcn_mfma_f32_16x16x32_bf16(a[1], b, acc[1][nt], 0, 0, 0);
        }
#pragma unroll
        for (int nt = 0; nt < 8; ++nt) {
            int col = w * 128 + nt * 16 + lr;
            float eb = (half == 0) ? eb1[col] : 0.f;
#pragma unroll
            for (int m = 0; m < 2; ++m)
#pragma unroll
                for (int reg = 0; reg < 4; ++reg)
                    PQ[(size_t)(rb + m * 16 + lg * 4 + reg) * 1024 + half * 512 + col]
                        = f2bf(acc[m][nt][reg] + eb);
        }
    } else {
        bf16x8 a1[2];
#pragma unroll
        for (int m = 0; m < 2; ++m) {
            int row = rb + m * 16 + lr;
            u16x8 v = (u16x8)(unsigned short)0;
            if (lg == 0) {
                int ac = act[row / KOBJ];
                v[ac & 3] = (unsigned short)0x3f80;    // bf16(1.0) at k=32+ac
            }
            a1[m] = __builtin_bit_cast(bf16x8, v);
        }
        f32x4 acc[2][8] = {};
#pragma unroll
        for (int nt = 0; nt < 8; ++nt) {
            int col = w * 128 + nt * 16 + lr;
            bf16x8 b0 = __builtin_bit_cast(bf16x8, *(const u16x8*)(nw1p + ((size_t)lg * 512 + col) * 8));
            bf16x8 b1 = __builtin_bit_cast(bf16x8, *(const u16x8*)(nw1p + ((size_t)(4 + lg) * 512 + col) * 8));
#pragma unroll
            for (int m = 0; m < 2; ++m) {
                acc[m][nt] = __builtin_amdgcn_mfma_f32_16x16x32_bf16(a[m], b0, acc[m][nt], 0, 0, 0);
                acc[m][nt] = __builtin_amdgcn_mfma_f32_16x16x32_bf16(a1[m], b1, acc[m][nt], 0, 0, 0);
            }
        }
#pragma unroll
        for (int nt = 0; nt < 8; ++nt) {
            int col = w * 128 + nt * 16 + lr;
            float bb = nbf[col];
#pragma unroll
            for (int m = 0; m < 2; ++m)
#pragma unroll
                for (int reg = 0; reg < 4; ++reg)
                    R[(size_t)(rb + m * 16 + lg * 4 + reg) * 512 + col] = acc[m][nt][reg] + bb;
        }
    }
}

// ---------------------------------------------------------------------------
// edge_v7: one half-graph per block (45 edges pad 48). 512 thr = 8 waves,
// wave w: cols w*64 (4 nt), rows 0..47 (3 m). BK=32, B gl_lds dbuf,
// A in-reg build (1-step prefetch) -> stride-40 LDS. Epilogue: LN, col-major
// stage (stride 56 u16), per-node 9-row sum -> S (bf16). No H2e.
__global__ __launch_bounds__(512, 4) void edge_v7(
    const unsigned short* __restrict__ PQ, const unsigned short* __restrict__ ew2p,
    const float* __restrict__ eb2, const float* __restrict__ eg,
    const float* __restrict__ ebt, unsigned short* __restrict__ S)
{
    __shared__ __align__(16) unsigned short Bsh[2][16384];  // 2 x 32KB; [buf][lg*512+col][8]
    __shared__ __align__(16) unsigned short Ash[2][1920];   // 2 x 3.75KB; [row*40 + k]
    __shared__ float sums[48], ssums[48];

    const int t = threadIdx.x, w = t >> 6, lane = t & 63;
    const int lr = lane & 15, lg = lane >> 4;
    const int g = blockIdx.x >> 1, half = blockIdx.x & 1;

    if (t < 48) { sums[t] = 0.f; ssums[t] = 0.f; }

    // A-build: 384 tasks = 48 rows x 8 half-granules (4 bf16 = 8B each)
    const bool ab = (t < 384);
    const int arow = t >> 3, ahg = t & 7;
    const bool avalid = ab && (arow < 45);
    int ai = 0, aj = 1;
    if (avalid) {
        int e = half * 45 + arow;
        ai = e / 9; int jj = e - ai * 9; aj = jj + (jj >= ai);
    }
    const unsigned short* pqP = PQ + ((size_t)(g * KOBJ + ai)) * 1024 + ahg * 4;
    const unsigned short* pqQ = PQ + ((size_t)(g * KOBJ + aj)) * 1024 + 512 + ahg * 4;

    u16x4 rp = (u16x4)(unsigned short)0, rq = (u16x4)(unsigned short)0;
    auto loadPQ = [&](int kc) {
        if (avalid) {
            rp = *(const u16x4*)(pqP + kc * 32);
            rq = *(const u16x4*)(pqQ + kc * 32);
        }
    };
    auto buildA = [&](int buf) {
        if (ab) {
            u16x4 o;
#pragma unroll
            for (int q = 0; q < 4; ++q) {
                float v = fmaxf(bf2f(rp[q]) + bf2f(rq[q]), 0.f);
                __bf16 h = (__bf16)v;
                o[q] = __builtin_bit_cast(unsigned short, h);
            }
            if (!avalid) o = (u16x4)(unsigned short)0;
            *(u16x4*)(&Ash[buf][arow * 40 + ahg * 4]) = o;
        }
    };
    auto fillB = [&](int kc, int buf) {
        char* Bb = (char*)&Bsh[buf][0];
#pragma unroll
        for (int RR = 0; RR < 4; ++RR)
            gl_lds16(ew2p + (size_t)kc * 16384 + RR * 4096 + t * 8, Bb + RR * 8192 + w * 1024);
    };

    f32x4 acc[3][4] = {};
    loadPQ(0); buildA(0); loadPQ(1); fillB(0, 0);
    __syncthreads();
    int cur = 0;
    for (int kc = 0; kc < 16; ++kc) {
        if (kc < 15) {
            fillB(kc + 1, cur ^ 1);
            buildA(cur ^ 1);                   // consumes regs prefetched for kc+1
            if (kc < 14) loadPQ(kc + 2);
        }
        const unsigned short* Ab = &Ash[cur][0];
        const unsigned short* Bb = &Bsh[cur][0];
        bf16x8 a0 = *(const bf16x8*)(Ab + ( 0 + lr) * 40 + lg * 8);
        bf16x8 a1 = *(const bf16x8*)(Ab + (16 + lr) * 40 + lg * 8);
        bf16x8 a2 = *(const bf16x8*)(Ab + (32 + lr) * 40 + lg * 8);
#pragma unroll
        for (int nt = 0; nt < 4; ++nt) {
            bf16x8 b = *(const bf16x8*)(Bb + ((size_t)lg * 512 + w * 64 + nt * 16 + lr) * 8);
            acc[0][nt] = __builtin_amdgcn_mfma_f32_16x16x32_bf16(a0, b, acc[0][nt], 0, 0, 0);
            acc[1][nt] = __builtin_amdgcn_mfma_f32_16x16x32_bf16(a1, b, acc[1][nt], 0, 0, 0);
            acc[2][nt] = __builtin_amdgcn_mfma_f32_16x16x32_bf16(a2, b, acc[2][nt], 0, 0, 0);
        }
        __syncthreads();
        cur ^= 1;
    }

    // ---- epilogue: +eb2, LN stats (cross-wave LDS), normalize, relu, stage ----
    float b2[4], gv[4], bb[4];
#pragma unroll
    for (int nt = 0; nt < 4; ++nt) {
        int c = w * 64 + nt * 16 + lr;
        b2[nt] = eb2[c]; gv[nt] = eg[c]; bb[nt] = ebt[c];
    }
#pragma unroll
    for (int m = 0; m < 3; ++m)
#pragma unroll
        for (int reg = 0; reg < 4; ++reg) {
            float s = 0.f, ss = 0.f;
#pragma unroll
            for (int nt = 0; nt < 4; ++nt) {
                float v = acc[m][nt][reg] + b2[nt];
                acc[m][nt][reg] = v;
                s += v; ss += v * v;
            }
#pragma unroll
            for (int msk = 1; msk < 16; msk <<= 1) {
                s  += __shfl_xor(s,  msk, 64);
                ss += __shfl_xor(ss, msk, 64);
            }
            if (lr == 0) {
                int row = m * 16 + lg * 4 + reg;
                atomicAdd(&sums[row], s);
                atomicAdd(&ssums[row], ss);
            }
        }
    __syncthreads();

    // normalize + stage col-major into dead Bsh: Hcol[col][row], stride 56 u16
    unsigned short* Hcol = &Bsh[0][0];        // 512*56 u16 = 56KB <= 64KB
#pragma unroll
    for (int m = 0; m < 3; ++m) {
#pragma unroll
        for (int nt = 0; nt < 4; ++nt) {
            int c = w * 64 + nt * 16 + lr;
            u16x4 o;
#pragma unroll
            for (int reg = 0; reg < 4; ++reg) {
                int row = m * 16 + lg * 4 + reg;
                float mean = sums[row] * (1.f / 512.f);
                float var  = ssums[row] * (1.f / 512.f) - mean * mean;
                float inv  = rsqrtf(var + LN_EPS);
                float h = fmaxf((acc[m][nt][reg] - mean) * inv * gv[nt] + bb[nt], 0.f);
                o[reg] = f2bf(h);
            }
            *(u16x4*)(&Hcol[c * 56 + m * 16 + lg * 4]) = o;
        }
    }
    __syncthreads();

    // per-node sums: thread t = column c; 5 nodes x 9 rows each
    {
        int c = t;
        u16x8 ch[6];
#pragma unroll
        for (int q = 0; q < 6; ++q)
            ch[q] = *(const u16x8*)(&Hcol[c * 56 + q * 8]);
        const size_t sbase = ((size_t)(g * KOBJ + half * 5)) * 512 + c;
#pragma unroll
        for (int n = 0; n < 5; ++n) {
            float s = 0.f;
#pragma unroll
            for (int k = 0; k < 9; ++k) {
                int r = n * 9 + k;
                s += bf2f(ch[r >> 3][r & 7]);
            }
            S[sbase + (size_t)n * 512] = f2bf(s);
        }
    }
}

// ---------------------------------------------------------------------------
// Hh = relu(S @ Wfp + R).  M=32/block, BK=64, gl_lds staged. 320 blocks.
__global__ __launch_bounds__(512, 4) void node_hh(
    const unsigned short* __restrict__ S, const unsigned short* __restrict__ Wfp,
    const float* __restrict__ R, unsigned short* __restrict__ Hh)
{
    __shared__ __align__(16) unsigned short Bt[32768];
    __shared__ __align__(16) unsigned short At[2048];
    const int t = threadIdx.x, w = t >> 6, lane = t & 63;
    const int lr = lane & 15, lg = lane >> 4;
    const int rb = blockIdx.x * 32;

    f32x4 acc[2][4] = {};
    for (int kc = 0; kc < 8; ++kc) {
        __syncthreads();
#pragma unroll
        for (int RR = 0; RR < 8; ++RR)
            gl_lds16(Wfp + ((size_t)kc * 4096 + RR * 512 + t) * 8,
                     (char*)Bt + RR * 8192 + w * 1024);
        if (w < 4) {
            int row = t >> 3, cp = t & 7;
            int scol = cp ^ (row & 7);
            gl_lds16(S + (size_t)(rb + row) * 512 + kc * 64 + scol * 8,
                     (char*)At + (t & ~63) * 16);
        }
        __syncthreads();
#pragma unroll
        for (int ks = 0; ks < 2; ++ks) {
            int kidx = ks * 4 + lg;
            bf16x8 a0 = *(const bf16x8*)(At + ( 0 + lr) * 64 + (kidx ^ (lr & 7)) * 8);
            bf16x8 a1 = *(const bf16x8*)(At + (16 + lr) * 64 + (kidx ^ (lr & 7)) * 8);
#pragma unroll
            for (int nt = 0; nt < 4; ++nt) {
                bf16x8 b = *(const bf16x8*)(Bt + ((size_t)kidx * 512 + w * 64 + nt * 16 + lr) * 8);
                acc[0][nt] = __builtin_amdgcn_mfma_f32_16x16x32_bf16(a0, b, acc[0][nt], 0, 0, 0);
                acc[1][nt] = __builtin_amdgcn_mfma_f32_16x16x32_bf16(a1, b, acc[1][nt], 0, 0, 0);
            }
        }
    }
#pragma unroll
    for (int m = 0; m < 2; ++m)
#pragma unroll
        for (int reg = 0; reg < 4; ++reg) {
            int row = rb + m * 16 + lg * 4 + reg;
#pragma unroll
            for (int nt = 0; nt < 4; ++nt) {
                int c = w * 64 + nt * 16 + lr;
                float v = acc[m][nt][reg] + R[(size_t)row * 512 + c];
                Hh[(size_t)row * 512 + c] = f2bf(fmaxf(v, 0.f));
            }
        }
}

// ---------------------------------------------------------------------------
// H2 = relu(LN(Hh@nw2 + nb2)*ng+nbt)  (bf16 out).
__global__ __launch_bounds__(512, 4) void node_ln(
    const unsigned short* __restrict__ A, const unsigned short* __restrict__ Wp,
    const float* __restrict__ bias, const float* __restrict__ gamma,
    const float* __restrict__ beta, unsigned short* __restrict__ outb)
{
    __shared__ __align__(16) unsigned short Bt[32768];
    __shared__ __align__(16) unsigned short At[2048];
    __shared__ float sums[32], ssums[32];
    const int t = threadIdx.x, w = t >> 6, lane = t & 63;
    const int lr = lane & 15, lg = lane >> 4;
    const int rb = blockIdx.x * 32;
    if (t < 32) { sums[t] = 0.f; ssums[t] = 0.f; }

    f32x4 acc[2][4] = {};
    for (int kc = 0; kc < 8; ++kc) {
        __syncthreads();
#pragma unroll
        for (int RR = 0; RR < 8; ++RR)
            gl_lds16(Wp + ((size_t)kc * 4096 + RR * 512 + t) * 8,
                     (char*)Bt + RR * 8192 + w * 1024);
        if (w < 4) {
            int row = t >> 3, cp = t & 7;
            int scol = cp ^ (row & 7);
            gl_lds16(A + (size_t)(rb + row) * 512 + kc * 64 + scol * 8,
                     (char*)At + (t & ~63) * 16);
        }
        __syncthreads();
#pragma unroll
        for (int ks = 0; ks < 2; ++ks) {
            int kidx = ks * 4 + lg;
            bf16x8 a0 = *(const bf16x8*)(At + ( 0 + lr) * 64 + (kidx ^ (lr & 7)) * 8);
            bf16x8 a1 = *(const bf16x8*)(At + (16 + lr) * 64 + (kidx ^ (lr & 7)) * 8);
#pragma unroll
            for (int nt = 0; nt < 4; ++nt) {
                bf16x8 b = *(const bf16x8*)(Bt + ((size_t)kidx * 512 + w * 64 + nt * 16 + lr) * 8);
                acc[0][nt] = __builtin_amdgcn_mfma_f32_16x16x32_bf16(a0, b, acc[0][nt], 0, 0, 0);
                acc[1][nt] = __builtin_amdgcn_mfma_f32_16x16x32_bf16(a1, b, acc[1][nt], 0, 0, 0);
            }
        }
    }

    float bv[4], gv[4], be[4];
#pragma unroll
    for (int nt = 0; nt < 4; ++nt) {
        int c = w * 64 + nt * 16 + lr;
        bv[nt] = bias[c]; gv[nt] = gamma[c]; be[nt] = beta[c];
    }
#pragma unroll
    for (int m = 0; m < 2; ++m)
#pragma unroll
        for (int reg = 0; reg < 4; ++reg) {
            float s = 0.f, ss = 0.f;
#pragma unroll
            for (int nt = 0; nt < 4; ++nt) {
                float v = acc[m][nt][reg] + bv[nt];
                acc[m][nt][reg] = v;
                s += v; ss += v * v;
            }
#pragma unroll
            for (int msk = 1; msk < 16; msk <<= 1) {
                s  += __shfl_xor(s,  msk, 64);
                ss += __shfl_xor(ss, msk, 64);
            }
            if (lr == 0) {
                atomicAdd(&sums [m * 16 + lg * 4 + reg], s);
                atomicAdd(&ssums[m * 16 + lg * 4 + reg], ss);
            }
        }
    __syncthreads();
#pragma unroll
    for (int m = 0; m < 2; ++m)
#pragma unroll
        for (int reg = 0; reg < 4; ++reg) {
            int rl = m * 16 + lg * 4 + reg;
            float mean = sums[rl] * (1.f / 512.f);
            float var  = ssums[rl] * (1.f / 512.f) - mean * mean;
            float inv  = rsqrtf(var + LN_EPS);
#pragma unroll
            for (int nt = 0; nt < 4; ++nt) {
                float v = fmaxf((acc[m][nt][reg] - mean) * inv * gv[nt] + be[nt], 0.f);
                outb[(size_t)(rb + rl) * 512 + w * 64 + nt * 16 + lr] = f2bf(v);
            }
        }
}

// ---------------------------------------------------------------------------
// out[10240,32] = H2(bf16) @ nw3 + nb3 (f32 out)
__global__ __launch_bounds__(256) void out_v4(
    const unsigned short* __restrict__ H2, const float* __restrict__ W3,
    const float* __restrict__ b3, float* __restrict__ out)
{
    int t = threadIdx.x;
    int r = blockIdx.x * 8 + (t >> 5);
    int c = t & 31;
    const unsigned short* h = H2 + (size_t)r * HID;
    float acc = 0.f;
#pragma unroll 8
    for (int k8 = 0; k8 < 64; ++k8) {
        u16x8 hv = *(const u16x8*)(h + k8 * 8);
#pragma unroll
        for (int q = 0; q < 8; ++q)
            acc = fmaf(bf2f(hv[q]), W3[(k8 * 8 + q) * DIN + c], acc);
    }
    out[(size_t)r * DIN + c] = acc + b3[c];
}

// ---------------------------------------------------------------------------
extern "C" void kernel_launch(void* const* d_in, const int* in_sizes, int n_in,
                              void* d_out, int out_size, void* d_ws, size_t ws_size,
                              hipStream_t stream)
{
    const float* states = (const float*)d_in[0];
    const int*   action = (const int*)d_in[1];
    const float* ew1 = (const float*)d_in[2];
    const float* eb1 = (const float*)d_in[3];
    const float* ew2 = (const float*)d_in[4];
    const float* eb2 = (const float*)d_in[5];
    const float* eg  = (const float*)d_in[6];
    const float* ebt = (const float*)d_in[7];
    const float* ew3 = (const float*)d_in[8];
    const float* eb3 = (const float*)d_in[9];
    const float* nw1 = (const float*)d_in[10];
    const float* nb1 = (const float*)d_in[11];
    const float* nw2 = (const float*)d_in[12];
    const float* nb2 = (const float*)d_in[13];
    const float* ng  = (const float*)d_in[14];
    const float* nbt = (const float*)d_in[15];
    const float* nw3 = (const float*)d_in[16];
    const float* nb3 = (const float*)d_in[17];

    char* wsb = (char*)d_ws;
    unsigned short* PQ   = (unsigned short*)(wsb);               // 10240x1024 bf16
    unsigned short* S    = (unsigned short*)(wsb + 20971520);    // 10240x512 bf16
    float*          R    = (float*)         (wsb + 31457280);    // 10240x512 f32
    unsigned short* Hh   = (unsigned short*)(wsb + 52428800);    // 10240x512 bf16
    unsigned short* H2   = (unsigned short*)(wsb + 62914560);    // 10240x512 bf16
    unsigned short* ew1p = (unsigned short*)(wsb + 73400320);    // 32x1024
    unsigned short* ew2p = (unsigned short*)(wsb + 73465856);    // 512x512 packed
    unsigned short* nw1p = (unsigned short*)(wsb + 73990144);    // 576x512 packed
    unsigned short* nw2p = (unsigned short*)(wsb + 74579968);    // 512x512 packed
    unsigned short* Wfp  = (unsigned short*)(wsb + 75104256);    // 512x512 packed
    float*          nbf  = (float*)         (wsb + 75628544);    // 512 f32
    float* out = (float*)d_out;

    hipLaunchKernelGGL(megapack, dim3(3328), dim3(256), 0, stream,
                       ew1, ew2, nw1, nw2, ew1p, ew2p, nw1p, nw2p);
    hipLaunchKernelGGL(fold_w2, dim3(33), dim3(512), 0, stream,
                       ew3, nw1p, nw1, nb1, eb3, Wfp, nbf);
    hipLaunchKernelGGL(pq_xa, dim3(320, 3), dim3(256), 0, stream,
                       states, action, ew1p, nw1p, eb1, nbf, PQ, R);
    hipLaunchKernelGGL(edge_v7, dim3(2 * NGRAPH), dim3(512), 0, stream,
                       PQ, ew2p, eb2, eg, ebt, S);
    hipLaunchKernelGGL(node_hh, dim3(320), dim3(512), 0, stream, S, Wfp, R, Hh);
    hipLaunchKernelGGL(node_ln, dim3(320), dim3(512), 0, stream, Hh, nw2p, nb2, ng, nbt, H2);
    hipLaunchKernelGGL(out_v4, dim3(NNODES / 8), dim3(256), 0, stream, H2, nw3, nb3, out);
}